// Round 1
// baseline (1384.317 us; speedup 1.0000x reference)
//
#include <hip/hip_runtime.h>
#include <hip/hip_bf16.h>

// ---------------------------------------------------------------------------
// ReformerBlockPreLN on MI355X — round 0 baseline (correctness-first)
// B=2 S=4096 D=1024 H=16 DH=64 R=2 NBUCK=64 CHUNK=128 MLP=4096
// ---------------------------------------------------------------------------

typedef short short8 __attribute__((ext_vector_type(8)));
typedef float f32x4 __attribute__((ext_vector_type(4)));
typedef unsigned short us4 __attribute__((ext_vector_type(4)));
typedef _Float16 half2v __attribute__((ext_vector_type(2)));

__device__ __forceinline__ unsigned short f2bf(float f) {
  unsigned u = __builtin_bit_cast(unsigned, f);
  u += 0x7FFFu + ((u >> 16) & 1u);
  return (unsigned short)(u >> 16);
}

__device__ __forceinline__ float gelu_f(float x) {
  float x3 = x * x * x;
  float t = tanhf(0.7978845608028654f * (x + 0.044715f * x3));
  return 0.5f * x * (1.0f + t);
}

__device__ __forceinline__ float fdot2f(half2v a, half2v b, float c) {
#if __has_builtin(__builtin_amdgcn_fdot2)
  return __builtin_amdgcn_fdot2(a, b, c, false);
#else
  float r;
  asm("v_dot2_f32_f16 %0, %1, %2, %3"
      : "=v"(r)
      : "v"(__builtin_bit_cast(float, a)), "v"(__builtin_bit_cast(float, b)),
        "v"(c));
  return r;
#endif
}

// ---------------------------------------------------------------------------
// transpose + cast fp32 [R][C] -> bf16 [C][R]
// ---------------------------------------------------------------------------
__global__ __launch_bounds__(256) void transpose_cast(
    const float* __restrict__ in, unsigned short* __restrict__ out, int R,
    int C) {
  __shared__ float tile[32][33];
  int ctiles = C >> 5;
  int bx = blockIdx.x % ctiles;
  int by = blockIdx.x / ctiles;
  int tx = threadIdx.x & 31;
  int ty = threadIdx.x >> 5;
#pragma unroll
  for (int i = 0; i < 32; i += 8)
    tile[ty + i][tx] = in[(size_t)(by * 32 + ty + i) * C + bx * 32 + tx];
  __syncthreads();
#pragma unroll
  for (int i = 0; i < 32; i += 8)
    out[(size_t)(bx * 32 + ty + i) * R + by * 32 + tx] = f2bf(tile[tx][ty + i]);
}

// ---------------------------------------------------------------------------
// LayerNorm over D=1024, fp32 in -> bf16 out. One block per row.
// ---------------------------------------------------------------------------
__global__ __launch_bounds__(256) void ln_bf16(const float* __restrict__ x,
                                               const float* __restrict__ sc,
                                               const float* __restrict__ bi,
                                               unsigned short* __restrict__ y) {
  int row = blockIdx.x, tid = threadIdx.x, lane = tid & 63, wv = tid >> 6;
  const float* xr = x + (size_t)row * 1024;
  float4 v = *(const float4*)(xr + tid * 4);
  float s1 = v.x + v.y + v.z + v.w;
  float s2 = v.x * v.x + v.y * v.y + v.z * v.z + v.w * v.w;
#pragma unroll
  for (int o = 1; o < 64; o <<= 1) {
    s1 += __shfl_xor(s1, o);
    s2 += __shfl_xor(s2, o);
  }
  __shared__ float a1[4], a2[4];
  if (lane == 0) {
    a1[wv] = s1;
    a2[wv] = s2;
  }
  __syncthreads();
  s1 = a1[0] + a1[1] + a1[2] + a1[3];
  s2 = a2[0] + a2[1] + a2[2] + a2[3];
  float mu = s1 * (1.f / 1024.f);
  float var = s2 * (1.f / 1024.f) - mu * mu;
  float rs = rsqrtf(var + 1e-6f);
  int c = tid * 4;
  us4 o4;
  o4.x = f2bf((v.x - mu) * rs * sc[c + 0] + bi[c + 0]);
  o4.y = f2bf((v.y - mu) * rs * sc[c + 1] + bi[c + 1]);
  o4.z = f2bf((v.z - mu) * rs * sc[c + 2] + bi[c + 2]);
  o4.w = f2bf((v.w - mu) * rs * sc[c + 3] + bi[c + 3]);
  *(us4*)(y + (size_t)row * 1024 + c) = o4;
}

// ---------------------------------------------------------------------------
// bf16 GEMM, C = A[M][K] * B with Bt[N][K] storage. 128x128 tile, BK=32,
// 16x16x32 MFMA, reg-staged double-buffered LDS.
// EPI 0: fp32 store. EPI 1: bias+gelu -> bf16. EPI 2: res (+bias) -> fp32.
// ---------------------------------------------------------------------------
#define GBM 128
#define GBN 128
#define GBK 32

template <int EPI>
__global__ __launch_bounds__(256) void gemm_bt(
    const unsigned short* __restrict__ A, const unsigned short* __restrict__ Bt,
    const float* __restrict__ bias, const float* __restrict__ res,
    float* __restrict__ Cf, unsigned short* __restrict__ Cb, int M, int N,
    int K) {
  __shared__ unsigned short sA[2][GBM * GBK];
  __shared__ unsigned short sB[2][GBN * GBK];
  const int nbx = N / GBN;
  const int bx = blockIdx.x % nbx;
  const int by = blockIdx.x / nbx;
  const int tid = threadIdx.x;
  const int lane = tid & 63;
  const int wave = tid >> 6;
  const int wr = wave >> 1, wc = wave & 1;
  const int sr0 = tid >> 2;
  const int sc0 = (tid & 3) * 8;
  const unsigned short* Abase = A + (size_t)(by * GBM) * K;
  const unsigned short* Bbase = Bt + (size_t)(bx * GBN) * K;

  f32x4 acc[4][4];
#pragma unroll
  for (int m = 0; m < 4; ++m)
#pragma unroll
    for (int n = 0; n < 4; ++n) {
      f32x4 z = {0.f, 0.f, 0.f, 0.f};
      acc[m][n] = z;
    }

  const int KT = K / GBK;
  // prologue: stage k-tile 0
  {
    short8 ra0 = *(const short8*)(Abase + (size_t)sr0 * K + sc0);
    short8 ra1 = *(const short8*)(Abase + (size_t)(sr0 + 64) * K + sc0);
    short8 rb0 = *(const short8*)(Bbase + (size_t)sr0 * K + sc0);
    short8 rb1 = *(const short8*)(Bbase + (size_t)(sr0 + 64) * K + sc0);
    *(short8*)&sA[0][sr0 * GBK + sc0] = ra0;
    *(short8*)&sA[0][(sr0 + 64) * GBK + sc0] = ra1;
    *(short8*)&sB[0][sr0 * GBK + sc0] = rb0;
    *(short8*)&sB[0][(sr0 + 64) * GBK + sc0] = rb1;
  }
  int cur = 0;
  const int arow = wr * 64 + (lane & 15);
  const int brow = wc * 64 + (lane & 15);
  const int koff = (lane >> 4) * 8;

  for (int kt = 0; kt < KT; ++kt) {
    __syncthreads();
    short8 na0, na1, nb0, nb1;
    if (kt + 1 < KT) {
      const unsigned short* An = Abase + (size_t)(kt + 1) * GBK;
      const unsigned short* Bn = Bbase + (size_t)(kt + 1) * GBK;
      na0 = *(const short8*)(An + (size_t)sr0 * K + sc0);
      na1 = *(const short8*)(An + (size_t)(sr0 + 64) * K + sc0);
      nb0 = *(const short8*)(Bn + (size_t)sr0 * K + sc0);
      nb1 = *(const short8*)(Bn + (size_t)(sr0 + 64) * K + sc0);
    }
    short8 af[4], bfv[4];
#pragma unroll
    for (int m = 0; m < 4; ++m)
      af[m] = *(const short8*)&sA[cur][(arow + m * 16) * GBK + koff];
#pragma unroll
    for (int n = 0; n < 4; ++n)
      bfv[n] = *(const short8*)&sB[cur][(brow + n * 16) * GBK + koff];
#pragma unroll
    for (int m = 0; m < 4; ++m)
#pragma unroll
      for (int n = 0; n < 4; ++n)
        acc[m][n] = __builtin_amdgcn_mfma_f32_16x16x32_bf16(af[m], bfv[n],
                                                            acc[m][n], 0, 0, 0);
    if (kt + 1 < KT) {
      __syncthreads();
      *(short8*)&sA[cur ^ 1][sr0 * GBK + sc0] = na0;
      *(short8*)&sA[cur ^ 1][(sr0 + 64) * GBK + sc0] = na1;
      *(short8*)&sB[cur ^ 1][sr0 * GBK + sc0] = nb0;
      *(short8*)&sB[cur ^ 1][(sr0 + 64) * GBK + sc0] = nb1;
      cur ^= 1;
    }
  }

  const int r0 = by * GBM + wr * 64;
  const int c0 = bx * GBN + wc * 64;
#pragma unroll
  for (int m = 0; m < 4; ++m) {
#pragma unroll
    for (int n = 0; n < 4; ++n) {
#pragma unroll
      for (int i = 0; i < 4; ++i) {
        int rr = r0 + m * 16 + ((lane >> 4) << 2) + i;
        int cc = c0 + n * 16 + (lane & 15);
        float vacc = acc[m][n][i];
        if (EPI == 0) {
          Cf[(size_t)rr * N + cc] = vacc;
        } else if (EPI == 1) {
          float t = vacc + bias[cc];
          Cb[(size_t)rr * N + cc] = f2bf(gelu_f(t));
        } else {
          float t = vacc + res[(size_t)rr * N + cc];
          if (bias != nullptr) t += bias[cc];
          Cf[(size_t)rr * N + cc] = t;
        }
      }
    }
  }
}

// ---------------------------------------------------------------------------
// Buckets + norms. One wave per (b,h,s) token. Lane = dim (DH=64).
// rot[r][m] = sum_d xn[d]*rotations[d,r,m]; bucket = argmax over [rot,-rot].
// ---------------------------------------------------------------------------
__global__ __launch_bounds__(256) void bucket_kernel(
    const float* __restrict__ qk, const float* __restrict__ rot,
    float* __restrict__ norms, int* __restrict__ buckets) {
  __shared__ float rotl[64 * 64];
  __shared__ float xnl[4][64];
  int tid = threadIdx.x, lane = tid & 63, wv = tid >> 6;
  for (int i = tid; i < 4096; i += 256) rotl[i] = rot[i];
  __syncthreads();
  for (int it = 0; it < 8; ++it) {
    int g = (it * 4096 + blockIdx.x) * 4 + wv;  // [0, B*H*S)
    int bh = g >> 12;
    int s = g & 4095;
    int b = bh >> 4, h = bh & 15;
    const float* xr = qk + ((size_t)(b * 4096 + s) * 1024 + h * 64);
    float x = xr[lane];
    float ss = x * x;
#pragma unroll
    for (int o = 1; o < 64; o <<= 1) ss += __shfl_xor(ss, o);
    float nrm = sqrtf(ss);
    float rn = 1.f / (nrm + 1e-6f);
    if (lane == 0) norms[g] = nrm;
    xnl[wv][lane] = x * rn;
    __syncthreads();
    int r_ = lane >> 5, m_ = lane & 31;
    float a = 0.f;
#pragma unroll 16
    for (int d = 0; d < 64; ++d) a += xnl[wv][d] * rotl[d * 64 + r_ * 32 + m_];
    float bv;
    int bi;
    if (a >= 0.f) {
      bv = a;
      bi = m_;
    } else {
      bv = -a;
      bi = m_ + 32;
    }
#pragma unroll
    for (int o = 16; o >= 1; o >>= 1) {
      float ov = __shfl_xor(bv, o);
      int oi = __shfl_xor(bi, o);
      if (ov > bv || (ov == bv && oi < bi)) {
        bv = ov;
        bi = oi;
      }
    }
    if (m_ == 0) buckets[((size_t)bh * 2 + r_) * 4096 + s] = bi;
    __syncthreads();
  }
}

// ---------------------------------------------------------------------------
// Stable counting sort by bucket. One block (64 threads) per (b,h,r);
// thread t owns bucket t.
// ---------------------------------------------------------------------------
__global__ __launch_bounds__(64) void sort_kernel(
    const int* __restrict__ buckets, int* __restrict__ order) {
  __shared__ int offs[64];
  int bhr = blockIdx.x;
  const int* bk = buckets + (size_t)bhr * 4096;
  int t = threadIdx.x;
  int cnt = 0;
  for (int i = 0; i < 4096; ++i) cnt += (bk[i] == t) ? 1 : 0;
  offs[t] = cnt;
  __syncthreads();
  if (t == 0) {
    int acc = 0;
    for (int j = 0; j < 64; ++j) {
      int c2 = offs[j];
      offs[j] = acc;
      acc += c2;
    }
  }
  __syncthreads();
  int pos = offs[t];
  int* op = order + (size_t)bhr * 4096;
  for (int i = 0; i < 4096; ++i)
    if (bk[i] == t) op[pos++] = i;
}

// ---------------------------------------------------------------------------
// Chunked LSH attention. One block per (b,h,r,chunk); 128 threads = 1 query
// per thread; online softmax over 3 key chunks (own, prev, next, wrapped).
// q = raw qk, k = qk/(|qk|+1e-6), v raw. Self-mask: -1e5 where key token ==
// query token. Writes o (un-normalized by round weights) and logsumexp.
// ---------------------------------------------------------------------------
#define DHP 66  // padded f16 row stride (banks spread for staging writes)

__global__ __launch_bounds__(128) void lsh_attn(
    const float* __restrict__ qk, const float* __restrict__ vv,
    const float* __restrict__ norms, const int* __restrict__ order,
    float* __restrict__ o, float* __restrict__ slog) {
  __shared__ _Float16 kls[128][DHP];
  __shared__ _Float16 vls[128][DHP];
  __shared__ int btok[128];
  int blk = blockIdx.x;
  int c = blk & 31;
  int bhr = blk >> 5;
  int bh = bhr >> 1;
  int h = bh & 15, b = bh >> 4;
  const int* ord = order + (size_t)bhr * 4096;
  int tid = threadIdx.x;
  int myTok = ord[c * 128 + tid];

  const float* qrow = qk + ((size_t)(b * 4096 + myTok) * 1024 + h * 64);
  half2v q2[32];
  const float2* q2f = (const float2*)qrow;
#pragma unroll
  for (int e = 0; e < 32; ++e) {
    float2 t = q2f[e];
    half2v tmp;
    tmp.x = (_Float16)t.x;
    tmp.y = (_Float16)t.y;
    q2[e] = tmp;
  }
  float m = -1e30f, l = 0.f;
  half2v o2[32];
  {
    half2v zz;
    zz.x = (_Float16)0.f;
    zz.y = zz.x;
#pragma unroll
    for (int e = 0; e < 32; ++e) o2[e] = zz;
  }

  for (int st = 0; st < 3; ++st) {
    int kc = (st == 0) ? c : (st == 1) ? ((c + 31) & 31) : ((c + 1) & 31);
    __syncthreads();
    int ktok = ord[kc * 128 + tid];
    float rn = 1.f / (norms[(size_t)bh * 4096 + ktok] + 1e-6f);
    const float* krow = qk + ((size_t)(b * 4096 + ktok) * 1024 + h * 64);
    const float* vrow = vv + ((size_t)(b * 4096 + ktok) * 1024 + h * 64);
    half2v* kd = (half2v*)&kls[tid][0];
    half2v* vd = (half2v*)&vls[tid][0];
    const float4* k4 = (const float4*)krow;
    const float4* v4 = (const float4*)vrow;
#pragma unroll
    for (int e = 0; e < 16; ++e) {
      float4 kk = k4[e];
      float4 vw = v4[e];
      half2v t0, t1, t2, t3;
      t0.x = (_Float16)(kk.x * rn);
      t0.y = (_Float16)(kk.y * rn);
      t1.x = (_Float16)(kk.z * rn);
      t1.y = (_Float16)(kk.w * rn);
      t2.x = (_Float16)vw.x;
      t2.y = (_Float16)vw.y;
      t3.x = (_Float16)vw.z;
      t3.y = (_Float16)vw.w;
      kd[2 * e] = t0;
      kd[2 * e + 1] = t1;
      vd[2 * e] = t2;
      vd[2 * e + 1] = t3;
    }
    btok[tid] = ktok;
    __syncthreads();
    for (int j = 0; j < 128; ++j) {
      const half2v* kr = (const half2v*)&kls[j][0];
      float d0 = 0.f, d1 = 0.f, d2 = 0.f, d3 = 0.f;
#pragma unroll
      for (int e = 0; e < 32; e += 4) {
        d0 = fdot2f(q2[e + 0], kr[e + 0], d0);
        d1 = fdot2f(q2[e + 1], kr[e + 1], d1);
        d2 = fdot2f(q2[e + 2], kr[e + 2], d2);
        d3 = fdot2f(q2[e + 3], kr[e + 3], d3);
      }
      float dval = ((d0 + d1) + (d2 + d3)) * 0.125f;
      if (btok[j] == myTok) dval -= 1e5f;
      if (dval > m) {
        float scl = __expf(m - dval);
        l *= scl;
        half2v s2h;
        s2h.x = (_Float16)scl;
        s2h.y = s2h.x;
#pragma unroll
        for (int e = 0; e < 32; ++e) o2[e] = o2[e] * s2h;
        m = dval;
      }
      float p = __expf(dval - m);
      l += p;
      half2v p2;
      p2.x = (_Float16)p;
      p2.y = p2.x;
      const half2v* vr = (const half2v*)&vls[j][0];
#pragma unroll
      for (int e = 0; e < 32; ++e) o2[e] = o2[e] + p2 * vr[e];
    }
  }
  float invl = 1.f / l;
  float* orow = o + ((size_t)bhr * 4096 + myTok) * 64;
#pragma unroll
  for (int e = 0; e < 32; ++e) {
    orow[2 * e] = (float)o2[e].x * invl;
    orow[2 * e + 1] = (float)o2[e].y * invl;
  }
  slog[(size_t)bhr * 4096 + myTok] = logf(l) + m;
}

// ---------------------------------------------------------------------------
// Combine hash rounds: w = softmax over r of slog; att = sum_r w_r * o_r.
// One wave per (b,s,h); lane = dim. Writes bf16 [b,s,(h,e)].
// ---------------------------------------------------------------------------
__global__ __launch_bounds__(256) void combine_rounds(
    const float* __restrict__ o, const float* __restrict__ slog,
    unsigned short* __restrict__ att) {
  int g = blockIdx.x * 4 + (threadIdx.x >> 6);  // (b*S+s)*H + h
  int lane = threadIdx.x & 63;
  int h = g & 15;
  int bs = g >> 4;
  int b = bs >> 12;
  int s = bs & 4095;
  size_t base = ((size_t)(b * 16 + h) * 2) * 4096 + s;
  size_t i0 = base;
  size_t i1 = base + 4096;
  float s0 = slog[i0], s1 = slog[i1];
  float mx = fmaxf(s0, s1);
  float e0 = __expf(s0 - mx), e1 = __expf(s1 - mx);
  float w0 = e0 / (e0 + e1);
  float w1 = 1.f - w0;
  float v0 = o[i0 * 64 + lane];
  float v1 = o[i1 * 64 + lane];
  att[(size_t)bs * 1024 + h * 64 + lane] = f2bf(w0 * v0 + w1 * v1);
}

// ---------------------------------------------------------------------------
extern "C" void kernel_launch(void* const* d_in, const int* in_sizes, int n_in,
                              void* d_out, int out_size, void* d_ws,
                              size_t ws_size, hipStream_t stream) {
  const float* inputs = (const float*)d_in[0];
  const float* ln1s = (const float*)d_in[1];
  const float* ln1b = (const float*)d_in[2];
  const float* wqk = (const float*)d_in[3];
  const float* wv = (const float*)d_in[4];
  const float* wout = (const float*)d_in[5];
  const float* rot = (const float*)d_in[6];
  const float* ln2s = (const float*)d_in[7];
  const float* ln2b = (const float*)d_in[8];
  const float* wm1 = (const float*)d_in[9];
  const float* bm1 = (const float*)d_in[10];
  const float* wm2 = (const float*)d_in[11];
  const float* bm2 = (const float*)d_in[12];

  char* w = (char*)d_ws;
  auto alloc = [&](size_t bytes) {
    char* p = w;
    w += (bytes + 255) & ~(size_t)255;
    return p;
  };
  unsigned short* wqk_bt = (unsigned short*)alloc(1024ull * 1024 * 2);
  unsigned short* wv_bt = (unsigned short*)alloc(1024ull * 1024 * 2);
  unsigned short* wout_bt = (unsigned short*)alloc(1024ull * 1024 * 2);
  unsigned short* wm1_bt = (unsigned short*)alloc(4096ull * 1024 * 2);
  unsigned short* wm2_bt = (unsigned short*)alloc(1024ull * 4096 * 2);
  unsigned short* bufA = (unsigned short*)alloc(8192ull * 1024 * 2);
  float* qkf = (float*)alloc(8192ull * 1024 * 4);
  float* vf = (float*)alloc(8192ull * 1024 * 4);  // later reused as x2
  float* norms = (float*)alloc(2ull * 16 * 4096 * 4);
  int* buckets = (int*)alloc(64ull * 4096 * 4);
  int* order = (int*)alloc(64ull * 4096 * 4);
  float* obuf = (float*)alloc(64ull * 4096 * 64 * 4);  // reused as h1 (bf16)
  float* slogb = (float*)alloc(64ull * 4096 * 4);
  float* x2 = vf;
  unsigned short* h1 = (unsigned short*)obuf;

  // weight transposes -> bf16 Bt layouts
  transpose_cast<<<32 * 32, 256, 0, stream>>>(wqk, wqk_bt, 1024, 1024);
  transpose_cast<<<32 * 32, 256, 0, stream>>>(wv, wv_bt, 1024, 1024);
  transpose_cast<<<32 * 32, 256, 0, stream>>>(wout, wout_bt, 1024, 1024);
  transpose_cast<<<32 * 128, 256, 0, stream>>>(wm1, wm1_bt, 1024, 4096);
  transpose_cast<<<128 * 32, 256, 0, stream>>>(wm2, wm2_bt, 4096, 1024);

  // LN1
  ln_bf16<<<8192, 256, 0, stream>>>(inputs, ln1s, ln1b, bufA);

  // qk / v projections
  gemm_bt<0><<<64 * 8, 256, 0, stream>>>(bufA, wqk_bt, nullptr, nullptr, qkf,
                                         nullptr, 8192, 1024, 1024);
  gemm_bt<0><<<64 * 8, 256, 0, stream>>>(bufA, wv_bt, nullptr, nullptr, vf,
                                         nullptr, 8192, 1024, 1024);

  // buckets + norms, sort, attention, round combine
  bucket_kernel<<<4096, 256, 0, stream>>>(qkf, rot, norms, buckets);
  sort_kernel<<<64, 64, 0, stream>>>(buckets, order);
  lsh_attn<<<2048, 128, 0, stream>>>(qkf, vf, norms, order, obuf, slogb);
  combine_rounds<<<32768, 256, 0, stream>>>(obuf, slogb, bufA);

  // out-projection + residual -> x2 (stored in vf)
  gemm_bt<2><<<64 * 8, 256, 0, stream>>>(bufA, wout_bt, nullptr, inputs, x2,
                                         nullptr, 8192, 1024, 1024);
  // LN2
  ln_bf16<<<8192, 256, 0, stream>>>(x2, ln2s, ln2b, bufA);
  // MLP1 + bias + gelu -> bf16
  gemm_bt<1><<<64 * 32, 256, 0, stream>>>(bufA, wm1_bt, bm1, nullptr, nullptr,
                                          h1, 8192, 4096, 1024);
  // MLP2 + bias + residual -> out
  gemm_bt<2><<<64 * 8, 256, 0, stream>>>(h1, wm2_bt, bm2, x2, (float*)d_out,
                                         nullptr, 8192, 1024, 4096);
}

// Round 2
// 862.496 us; speedup vs baseline: 1.6050x; 1.6050x over previous
//
#include <hip/hip_runtime.h>
#include <hip/hip_bf16.h>

// ---------------------------------------------------------------------------
// ReformerBlockPreLN on MI355X — round 1: MFMA-based LSH attention
// B=2 S=4096 D=1024 H=16 DH=64 R=2 NBUCK=64 CHUNK=128 MLP=4096
// ---------------------------------------------------------------------------

typedef short short8 __attribute__((ext_vector_type(8)));
typedef float f32x4 __attribute__((ext_vector_type(4)));
typedef unsigned short us4 __attribute__((ext_vector_type(4)));

__device__ __forceinline__ unsigned short f2bf(float f) {
  unsigned u = __builtin_bit_cast(unsigned, f);
  u += 0x7FFFu + ((u >> 16) & 1u);
  return (unsigned short)(u >> 16);
}

__device__ __forceinline__ float gelu_f(float x) {
  float x3 = x * x * x;
  float t = tanhf(0.7978845608028654f * (x + 0.044715f * x3));
  return 0.5f * x * (1.0f + t);
}

// ---------------------------------------------------------------------------
// transpose + cast fp32 [R][C] -> bf16 [C][R]
// ---------------------------------------------------------------------------
__global__ __launch_bounds__(256) void transpose_cast(
    const float* __restrict__ in, unsigned short* __restrict__ out, int R,
    int C) {
  __shared__ float tile[32][33];
  int ctiles = C >> 5;
  int bx = blockIdx.x % ctiles;
  int by = blockIdx.x / ctiles;
  int tx = threadIdx.x & 31;
  int ty = threadIdx.x >> 5;
#pragma unroll
  for (int i = 0; i < 32; i += 8)
    tile[ty + i][tx] = in[(size_t)(by * 32 + ty + i) * C + bx * 32 + tx];
  __syncthreads();
#pragma unroll
  for (int i = 0; i < 32; i += 8)
    out[(size_t)(bx * 32 + ty + i) * R + by * 32 + tx] = f2bf(tile[tx][ty + i]);
}

// ---------------------------------------------------------------------------
// LayerNorm over D=1024, fp32 in -> bf16 out. One block per row.
// ---------------------------------------------------------------------------
__global__ __launch_bounds__(256) void ln_bf16(const float* __restrict__ x,
                                               const float* __restrict__ sc,
                                               const float* __restrict__ bi,
                                               unsigned short* __restrict__ y) {
  int row = blockIdx.x, tid = threadIdx.x, lane = tid & 63, wv = tid >> 6;
  const float* xr = x + (size_t)row * 1024;
  float4 v = *(const float4*)(xr + tid * 4);
  float s1 = v.x + v.y + v.z + v.w;
  float s2 = v.x * v.x + v.y * v.y + v.z * v.z + v.w * v.w;
#pragma unroll
  for (int o = 1; o < 64; o <<= 1) {
    s1 += __shfl_xor(s1, o);
    s2 += __shfl_xor(s2, o);
  }
  __shared__ float a1[4], a2[4];
  if (lane == 0) {
    a1[wv] = s1;
    a2[wv] = s2;
  }
  __syncthreads();
  s1 = a1[0] + a1[1] + a1[2] + a1[3];
  s2 = a2[0] + a2[1] + a2[2] + a2[3];
  float mu = s1 * (1.f / 1024.f);
  float var = s2 * (1.f / 1024.f) - mu * mu;
  float rs = rsqrtf(var + 1e-6f);
  int c = tid * 4;
  us4 o4;
  o4.x = f2bf((v.x - mu) * rs * sc[c + 0] + bi[c + 0]);
  o4.y = f2bf((v.y - mu) * rs * sc[c + 1] + bi[c + 1]);
  o4.z = f2bf((v.z - mu) * rs * sc[c + 2] + bi[c + 2]);
  o4.w = f2bf((v.w - mu) * rs * sc[c + 3] + bi[c + 3]);
  *(us4*)(y + (size_t)row * 1024 + c) = o4;
}

// ---------------------------------------------------------------------------
// bf16 GEMM, C = A[M][K] * B with Bt[N][K] storage. 128x128 tile, BK=32,
// 16x16x32 MFMA, reg-staged double-buffered LDS.
// EPI 0: fp32 store. EPI 1: bias+gelu -> bf16. EPI 2: res (+bias) -> fp32.
// ---------------------------------------------------------------------------
#define GBM 128
#define GBN 128
#define GBK 32

template <int EPI>
__global__ __launch_bounds__(256) void gemm_bt(
    const unsigned short* __restrict__ A, const unsigned short* __restrict__ Bt,
    const float* __restrict__ bias, const float* __restrict__ res,
    float* __restrict__ Cf, unsigned short* __restrict__ Cb, int M, int N,
    int K) {
  __shared__ unsigned short sA[2][GBM * GBK];
  __shared__ unsigned short sB[2][GBN * GBK];
  const int nbx = N / GBN;
  const int bx = blockIdx.x % nbx;
  const int by = blockIdx.x / nbx;
  const int tid = threadIdx.x;
  const int lane = tid & 63;
  const int wave = tid >> 6;
  const int wr = wave >> 1, wc = wave & 1;
  const int sr0 = tid >> 2;
  const int sc0 = (tid & 3) * 8;
  const unsigned short* Abase = A + (size_t)(by * GBM) * K;
  const unsigned short* Bbase = Bt + (size_t)(bx * GBN) * K;

  f32x4 acc[4][4];
#pragma unroll
  for (int m = 0; m < 4; ++m)
#pragma unroll
    for (int n = 0; n < 4; ++n) {
      f32x4 z = {0.f, 0.f, 0.f, 0.f};
      acc[m][n] = z;
    }

  const int KT = K / GBK;
  {
    short8 ra0 = *(const short8*)(Abase + (size_t)sr0 * K + sc0);
    short8 ra1 = *(const short8*)(Abase + (size_t)(sr0 + 64) * K + sc0);
    short8 rb0 = *(const short8*)(Bbase + (size_t)sr0 * K + sc0);
    short8 rb1 = *(const short8*)(Bbase + (size_t)(sr0 + 64) * K + sc0);
    *(short8*)&sA[0][sr0 * GBK + sc0] = ra0;
    *(short8*)&sA[0][(sr0 + 64) * GBK + sc0] = ra1;
    *(short8*)&sB[0][sr0 * GBK + sc0] = rb0;
    *(short8*)&sB[0][(sr0 + 64) * GBK + sc0] = rb1;
  }
  int cur = 0;
  const int arow = wr * 64 + (lane & 15);
  const int brow = wc * 64 + (lane & 15);
  const int koff = (lane >> 4) * 8;

  for (int kt = 0; kt < KT; ++kt) {
    __syncthreads();
    short8 na0, na1, nb0, nb1;
    if (kt + 1 < KT) {
      const unsigned short* An = Abase + (size_t)(kt + 1) * GBK;
      const unsigned short* Bn = Bbase + (size_t)(kt + 1) * GBK;
      na0 = *(const short8*)(An + (size_t)sr0 * K + sc0);
      na1 = *(const short8*)(An + (size_t)(sr0 + 64) * K + sc0);
      nb0 = *(const short8*)(Bn + (size_t)sr0 * K + sc0);
      nb1 = *(const short8*)(Bn + (size_t)(sr0 + 64) * K + sc0);
    }
    short8 af[4], bfv[4];
#pragma unroll
    for (int m = 0; m < 4; ++m)
      af[m] = *(const short8*)&sA[cur][(arow + m * 16) * GBK + koff];
#pragma unroll
    for (int n = 0; n < 4; ++n)
      bfv[n] = *(const short8*)&sB[cur][(brow + n * 16) * GBK + koff];
#pragma unroll
    for (int m = 0; m < 4; ++m)
#pragma unroll
      for (int n = 0; n < 4; ++n)
        acc[m][n] = __builtin_amdgcn_mfma_f32_16x16x32_bf16(af[m], bfv[n],
                                                            acc[m][n], 0, 0, 0);
    if (kt + 1 < KT) {
      __syncthreads();
      *(short8*)&sA[cur ^ 1][sr0 * GBK + sc0] = na0;
      *(short8*)&sA[cur ^ 1][(sr0 + 64) * GBK + sc0] = na1;
      *(short8*)&sB[cur ^ 1][sr0 * GBK + sc0] = nb0;
      *(short8*)&sB[cur ^ 1][(sr0 + 64) * GBK + sc0] = nb1;
      cur ^= 1;
    }
  }

  const int r0 = by * GBM + wr * 64;
  const int c0 = bx * GBN + wc * 64;
#pragma unroll
  for (int m = 0; m < 4; ++m) {
#pragma unroll
    for (int n = 0; n < 4; ++n) {
#pragma unroll
      for (int i = 0; i < 4; ++i) {
        int rr = r0 + m * 16 + ((lane >> 4) << 2) + i;
        int cc = c0 + n * 16 + (lane & 15);
        float vacc = acc[m][n][i];
        if (EPI == 0) {
          Cf[(size_t)rr * N + cc] = vacc;
        } else if (EPI == 1) {
          float t = vacc + bias[cc];
          Cb[(size_t)rr * N + cc] = f2bf(gelu_f(t));
        } else {
          float t = vacc + res[(size_t)rr * N + cc];
          if (bias != nullptr) t += bias[cc];
          Cf[(size_t)rr * N + cc] = t;
        }
      }
    }
  }
}

// ---------------------------------------------------------------------------
// Buckets + norms. One wave per (b,h,s) token.
// ---------------------------------------------------------------------------
__global__ __launch_bounds__(256) void bucket_kernel(
    const float* __restrict__ qk, const float* __restrict__ rot,
    float* __restrict__ norms, int* __restrict__ buckets) {
  __shared__ float rotl[64 * 64];
  __shared__ float xnl[4][64];
  int tid = threadIdx.x, lane = tid & 63, wv = tid >> 6;
  for (int i = tid; i < 4096; i += 256) rotl[i] = rot[i];
  __syncthreads();
  for (int it = 0; it < 8; ++it) {
    int g = (it * 4096 + blockIdx.x) * 4 + wv;
    int bh = g >> 12;
    int s = g & 4095;
    int b = bh >> 4, h = bh & 15;
    const float* xr = qk + ((size_t)(b * 4096 + s) * 1024 + h * 64);
    float x = xr[lane];
    float ss = x * x;
#pragma unroll
    for (int o = 1; o < 64; o <<= 1) ss += __shfl_xor(ss, o);
    float nrm = sqrtf(ss);
    float rn = 1.f / (nrm + 1e-6f);
    if (lane == 0) norms[g] = nrm;
    xnl[wv][lane] = x * rn;
    __syncthreads();
    int r_ = lane >> 5, m_ = lane & 31;
    float a = 0.f;
#pragma unroll 16
    for (int d = 0; d < 64; ++d) a += xnl[wv][d] * rotl[d * 64 + r_ * 32 + m_];
    float bv;
    int bi;
    if (a >= 0.f) {
      bv = a;
      bi = m_;
    } else {
      bv = -a;
      bi = m_ + 32;
    }
#pragma unroll
    for (int o = 16; o >= 1; o >>= 1) {
      float ov = __shfl_xor(bv, o);
      int oi = __shfl_xor(bi, o);
      if (ov > bv || (ov == bv && oi < bi)) {
        bv = ov;
        bi = oi;
      }
    }
    if (m_ == 0) buckets[((size_t)bh * 2 + r_) * 4096 + s] = bi;
    __syncthreads();
  }
}

// ---------------------------------------------------------------------------
// Stable counting sort by bucket. One block (64 threads) per (b,h,r).
// ---------------------------------------------------------------------------
__global__ __launch_bounds__(64) void sort_kernel(
    const int* __restrict__ buckets, int* __restrict__ order) {
  __shared__ int offs[64];
  int bhr = blockIdx.x;
  const int* bk = buckets + (size_t)bhr * 4096;
  int t = threadIdx.x;
  int cnt = 0;
  for (int i = 0; i < 4096; ++i) cnt += (bk[i] == t) ? 1 : 0;
  offs[t] = cnt;
  __syncthreads();
  if (t == 0) {
    int acc = 0;
    for (int j = 0; j < 64; ++j) {
      int c2 = offs[j];
      offs[j] = acc;
      acc += c2;
    }
  }
  __syncthreads();
  int pos = offs[t];
  int* op = order + (size_t)bhr * 4096;
  for (int i = 0; i < 4096; ++i)
    if (bk[i] == t) op[pos++] = i;
}

// ---------------------------------------------------------------------------
// MFMA LSH attention. One block per (b,h,r,chunk); 256 threads = 4 waves;
// wave wv owns q-rows [wv*32, wv*32+32). Per key chunk (own/prev/next):
// stage K (normalized bf16, stride 72) and V transposed (Vt[64][136]) in LDS,
// S = Q K^T via 16x16x32 MFMA, online softmax (fp32, running m/l per row),
// P -> bf16 in per-wave LDS, O += P V via MFMA. Epilogue: O/l, logsumexp.
// ---------------------------------------------------------------------------
#define KSTR 72
#define PSTR 136

__global__ __launch_bounds__(256, 2) void lsh_attn_mfma(
    const float* __restrict__ qk, const float* __restrict__ vv,
    const float* __restrict__ norms, const int* __restrict__ order,
    float* __restrict__ o, float* __restrict__ slog) {
  __shared__ unsigned short Kls[128 * KSTR];
  __shared__ unsigned short Vt[64 * PSTR];
  __shared__ unsigned short Pls[4][32 * PSTR];
  __shared__ int qtokL[128];
  __shared__ int btok[128];

  const int blk = blockIdx.x;
  const int c = blk & 31;
  const int bhr = blk >> 5;
  const int bh = bhr >> 1;
  const int h = bh & 15, b = bh >> 4;
  const int* ord = order + (size_t)bhr * 4096;
  const int tid = threadIdx.x, lane = tid & 63, wv = tid >> 6;
  const int l15 = lane & 15, lhi = lane >> 4;

  if (tid < 128) qtokL[tid] = ord[c * 128 + tid];
  __syncthreads();

  // Q fragments (raw qk, bf16), wave-private, constant across chunks.
  short8 qf[2][2];
#pragma unroll
  for (int mt = 0; mt < 2; ++mt) {
#pragma unroll
    for (int ks = 0; ks < 2; ++ks) {
      int row = wv * 32 + mt * 16 + l15;
      int tok = qtokL[row];
      const float* qp =
          qk + ((size_t)(b * 4096 + tok) * 1024 + h * 64) + ks * 32 + lhi * 8;
      float4 a0 = *(const float4*)qp;
      float4 a1 = *(const float4*)(qp + 4);
      short8 f;
      f[0] = (short)f2bf(a0.x);
      f[1] = (short)f2bf(a0.y);
      f[2] = (short)f2bf(a0.z);
      f[3] = (short)f2bf(a0.w);
      f[4] = (short)f2bf(a1.x);
      f[5] = (short)f2bf(a1.y);
      f[6] = (short)f2bf(a1.z);
      f[7] = (short)f2bf(a1.w);
      qf[mt][ks] = f;
    }
  }

  float mrun[2][4], lrun[2][4];
  f32x4 oacc[2][4];
#pragma unroll
  for (int mt = 0; mt < 2; ++mt)
#pragma unroll
    for (int i = 0; i < 4; ++i) {
      mrun[mt][i] = -1e30f;
      lrun[mt][i] = 0.f;
    }
#pragma unroll
  for (int mt = 0; mt < 2; ++mt)
#pragma unroll
    for (int n = 0; n < 4; ++n) {
      f32x4 z = {0.f, 0.f, 0.f, 0.f};
      oacc[mt][n] = z;
    }

  for (int st = 0; st < 3; ++st) {
    int kc = (st == 0) ? c : (st == 1) ? ((c + 31) & 31) : ((c + 1) & 31);
    __syncthreads();  // previous chunk's K/V reads complete
    {
      int row = tid >> 1, half = tid & 1;
      int ktok = ord[kc * 128 + row];
      if (half == 0) btok[row] = ktok;
      float rn = 1.f / (norms[(size_t)bh * 4096 + ktok] + 1e-6f);
      const float* kp =
          qk + ((size_t)(b * 4096 + ktok) * 1024 + h * 64) + half * 32;
      const float* vp =
          vv + ((size_t)(b * 4096 + ktok) * 1024 + h * 64) + half * 32;
#pragma unroll
      for (int i = 0; i < 8; ++i) {
        float4 kk = ((const float4*)kp)[i];
        us4 kb;
        kb.x = f2bf(kk.x * rn);
        kb.y = f2bf(kk.y * rn);
        kb.z = f2bf(kk.z * rn);
        kb.w = f2bf(kk.w * rn);
        *(us4*)&Kls[row * KSTR + half * 32 + i * 4] = kb;
        float4 vw = ((const float4*)vp)[i];
        int d0 = half * 32 + i * 4;
        Vt[(d0 + 0) * PSTR + row] = f2bf(vw.x);
        Vt[(d0 + 1) * PSTR + row] = f2bf(vw.y);
        Vt[(d0 + 2) * PSTR + row] = f2bf(vw.z);
        Vt[(d0 + 3) * PSTR + row] = f2bf(vw.w);
      }
    }
    __syncthreads();

    // S = Q K^T  (2 m-tiles x 8 n-tiles)
    f32x4 sacc[2][8];
#pragma unroll
    for (int mt = 0; mt < 2; ++mt)
#pragma unroll
      for (int n = 0; n < 8; ++n) {
        f32x4 z = {0.f, 0.f, 0.f, 0.f};
        sacc[mt][n] = z;
      }
#pragma unroll
    for (int ks = 0; ks < 2; ++ks) {
      short8 kf[8];
#pragma unroll
      for (int n = 0; n < 8; ++n)
        kf[n] = *(const short8*)&Kls[(n * 16 + l15) * KSTR + ks * 32 + lhi * 8];
#pragma unroll
      for (int mt = 0; mt < 2; ++mt)
#pragma unroll
        for (int n = 0; n < 8; ++n)
          sacc[mt][n] = __builtin_amdgcn_mfma_f32_16x16x32_bf16(
              qf[mt][ks], kf[n], sacc[mt][n], 0, 0, 0);
    }

    // online softmax; P -> bf16 LDS
    int ktA[8];
#pragma unroll
    for (int n = 0; n < 8; ++n) ktA[n] = btok[n * 16 + l15];
#pragma unroll
    for (int mt = 0; mt < 2; ++mt) {
#pragma unroll
      for (int i = 0; i < 4; ++i) {
        int qrow = wv * 32 + mt * 16 + lhi * 4 + i;
        int qt = qtokL[qrow];
        float sv[8];
        float mx = -1e30f;
#pragma unroll
        for (int n = 0; n < 8; ++n) {
          float s = sacc[mt][n][i] * 0.125f;
          if (ktA[n] == qt) s -= 1e5f;
          sv[n] = s;
          mx = fmaxf(mx, s);
        }
#pragma unroll
        for (int d = 1; d < 16; d <<= 1) mx = fmaxf(mx, __shfl_xor(mx, d));
        float mold = mrun[mt][i];
        float mnew = fmaxf(mold, mx);
        float scl = __expf(mold - mnew);
        lrun[mt][i] *= scl;
#pragma unroll
        for (int n = 0; n < 4; ++n) oacc[mt][n][i] *= scl;
        float ps = 0.f;
#pragma unroll
        for (int n = 0; n < 8; ++n) {
          float p = __expf(sv[n] - mnew);
          ps += p;
          Pls[wv][(mt * 16 + lhi * 4 + i) * PSTR + n * 16 + l15] = f2bf(p);
        }
#pragma unroll
        for (int d = 1; d < 16; d <<= 1) ps += __shfl_xor(ps, d);
        lrun[mt][i] = lrun[mt][i] + ps;
        mrun[mt][i] = mnew;
      }
    }

    // O += P V  (A-frags from Pls, B-frags from Vt)
#pragma unroll
    for (int ks = 0; ks < 4; ++ks) {
      short8 pf[2];
#pragma unroll
      for (int mt = 0; mt < 2; ++mt)
        pf[mt] =
            *(const short8*)&Pls[wv][(mt * 16 + l15) * PSTR + ks * 32 + lhi * 8];
      short8 vfr[4];
#pragma unroll
      for (int n = 0; n < 4; ++n)
        vfr[n] = *(const short8*)&Vt[(n * 16 + l15) * PSTR + ks * 32 + lhi * 8];
#pragma unroll
      for (int mt = 0; mt < 2; ++mt)
#pragma unroll
        for (int n = 0; n < 4; ++n)
          oacc[mt][n] = __builtin_amdgcn_mfma_f32_16x16x32_bf16(
              pf[mt], vfr[n], oacc[mt][n], 0, 0, 0);
    }
  }

  // epilogue
#pragma unroll
  for (int mt = 0; mt < 2; ++mt) {
#pragma unroll
    for (int i = 0; i < 4; ++i) {
      int qrow = wv * 32 + mt * 16 + lhi * 4 + i;
      int tok = qtokL[qrow];
      float l = lrun[mt][i];
      float invl = 1.f / l;
      if (l15 == 0) slog[(size_t)bhr * 4096 + tok] = logf(l) + mrun[mt][i];
      float* orow = o + ((size_t)bhr * 4096 + tok) * 64;
#pragma unroll
      for (int n = 0; n < 4; ++n) orow[n * 16 + l15] = oacc[mt][n][i] * invl;
    }
  }
}

// ---------------------------------------------------------------------------
// Combine hash rounds: w = softmax over r of slog; att = sum_r w_r * o_r.
// ---------------------------------------------------------------------------
__global__ __launch_bounds__(256) void combine_rounds(
    const float* __restrict__ o, const float* __restrict__ slog,
    unsigned short* __restrict__ att) {
  int g = blockIdx.x * 4 + (threadIdx.x >> 6);
  int lane = threadIdx.x & 63;
  int h = g & 15;
  int bs = g >> 4;
  int b = bs >> 12;
  int s = bs & 4095;
  size_t base = ((size_t)(b * 16 + h) * 2) * 4096 + s;
  size_t i0 = base;
  size_t i1 = base + 4096;
  float s0 = slog[i0], s1 = slog[i1];
  float mx = fmaxf(s0, s1);
  float e0 = __expf(s0 - mx), e1 = __expf(s1 - mx);
  float w0 = e0 / (e0 + e1);
  float w1 = 1.f - w0;
  float v0 = o[i0 * 64 + lane];
  float v1 = o[i1 * 64 + lane];
  att[(size_t)bs * 1024 + h * 64 + lane] = f2bf(w0 * v0 + w1 * v1);
}

// ---------------------------------------------------------------------------
extern "C" void kernel_launch(void* const* d_in, const int* in_sizes, int n_in,
                              void* d_out, int out_size, void* d_ws,
                              size_t ws_size, hipStream_t stream) {
  const float* inputs = (const float*)d_in[0];
  const float* ln1s = (const float*)d_in[1];
  const float* ln1b = (const float*)d_in[2];
  const float* wqk = (const float*)d_in[3];
  const float* wv = (const float*)d_in[4];
  const float* wout = (const float*)d_in[5];
  const float* rot = (const float*)d_in[6];
  const float* ln2s = (const float*)d_in[7];
  const float* ln2b = (const float*)d_in[8];
  const float* wm1 = (const float*)d_in[9];
  const float* bm1 = (const float*)d_in[10];
  const float* wm2 = (const float*)d_in[11];
  const float* bm2 = (const float*)d_in[12];

  char* w = (char*)d_ws;
  auto alloc = [&](size_t bytes) {
    char* p = w;
    w += (bytes + 255) & ~(size_t)255;
    return p;
  };
  unsigned short* wqk_bt = (unsigned short*)alloc(1024ull * 1024 * 2);
  unsigned short* wv_bt = (unsigned short*)alloc(1024ull * 1024 * 2);
  unsigned short* wout_bt = (unsigned short*)alloc(1024ull * 1024 * 2);
  unsigned short* wm1_bt = (unsigned short*)alloc(4096ull * 1024 * 2);
  unsigned short* wm2_bt = (unsigned short*)alloc(1024ull * 4096 * 2);
  unsigned short* bufA = (unsigned short*)alloc(8192ull * 1024 * 2);
  float* qkf = (float*)alloc(8192ull * 1024 * 4);
  float* vf = (float*)alloc(8192ull * 1024 * 4);  // later reused as x2
  float* norms = (float*)alloc(2ull * 16 * 4096 * 4);
  int* buckets = (int*)alloc(64ull * 4096 * 4);
  int* order = (int*)alloc(64ull * 4096 * 4);
  float* obuf = (float*)alloc(64ull * 4096 * 64 * 4);  // reused as h1 (bf16)
  float* slogb = (float*)alloc(64ull * 4096 * 4);
  float* x2 = vf;
  unsigned short* h1 = (unsigned short*)obuf;

  transpose_cast<<<32 * 32, 256, 0, stream>>>(wqk, wqk_bt, 1024, 1024);
  transpose_cast<<<32 * 32, 256, 0, stream>>>(wv, wv_bt, 1024, 1024);
  transpose_cast<<<32 * 32, 256, 0, stream>>>(wout, wout_bt, 1024, 1024);
  transpose_cast<<<32 * 128, 256, 0, stream>>>(wm1, wm1_bt, 1024, 4096);
  transpose_cast<<<128 * 32, 256, 0, stream>>>(wm2, wm2_bt, 4096, 1024);

  ln_bf16<<<8192, 256, 0, stream>>>(inputs, ln1s, ln1b, bufA);

  gemm_bt<0><<<64 * 8, 256, 0, stream>>>(bufA, wqk_bt, nullptr, nullptr, qkf,
                                         nullptr, 8192, 1024, 1024);
  gemm_bt<0><<<64 * 8, 256, 0, stream>>>(bufA, wv_bt, nullptr, nullptr, vf,
                                         nullptr, 8192, 1024, 1024);

  bucket_kernel<<<4096, 256, 0, stream>>>(qkf, rot, norms, buckets);
  sort_kernel<<<64, 64, 0, stream>>>(buckets, order);
  lsh_attn_mfma<<<2048, 256, 0, stream>>>(qkf, vf, norms, order, obuf, slogb);
  combine_rounds<<<32768, 256, 0, stream>>>(obuf, slogb, bufA);

  gemm_bt<2><<<64 * 8, 256, 0, stream>>>(bufA, wout_bt, nullptr, inputs, x2,
                                         nullptr, 8192, 1024, 1024);
  ln_bf16<<<8192, 256, 0, stream>>>(x2, ln2s, ln2b, bufA);
  gemm_bt<1><<<64 * 32, 256, 0, stream>>>(bufA, wm1_bt, bm1, nullptr, nullptr,
                                          h1, 8192, 4096, 1024);
  gemm_bt<2><<<64 * 8, 256, 0, stream>>>(h1, wm2_bt, bm2, x2, (float*)d_out,
                                         nullptr, 8192, 1024, 4096);
}

// Round 3
// 566.024 us; speedup vs baseline: 2.4457x; 1.5238x over previous
//
#include <hip/hip_runtime.h>
#include <hip/hip_bf16.h>

// ---------------------------------------------------------------------------
// ReformerBlockPreLN on MI355X — round 2: parallel stable counting sort
// B=2 S=4096 D=1024 H=16 DH=64 R=2 NBUCK=64 CHUNK=128 MLP=4096
// ---------------------------------------------------------------------------

typedef short short8 __attribute__((ext_vector_type(8)));
typedef float f32x4 __attribute__((ext_vector_type(4)));
typedef unsigned short us4 __attribute__((ext_vector_type(4)));

__device__ __forceinline__ unsigned short f2bf(float f) {
  unsigned u = __builtin_bit_cast(unsigned, f);
  u += 0x7FFFu + ((u >> 16) & 1u);
  return (unsigned short)(u >> 16);
}

__device__ __forceinline__ float gelu_f(float x) {
  float x3 = x * x * x;
  float t = tanhf(0.7978845608028654f * (x + 0.044715f * x3));
  return 0.5f * x * (1.0f + t);
}

// ---------------------------------------------------------------------------
// transpose + cast fp32 [R][C] -> bf16 [C][R]
// ---------------------------------------------------------------------------
__global__ __launch_bounds__(256) void transpose_cast(
    const float* __restrict__ in, unsigned short* __restrict__ out, int R,
    int C) {
  __shared__ float tile[32][33];
  int ctiles = C >> 5;
  int bx = blockIdx.x % ctiles;
  int by = blockIdx.x / ctiles;
  int tx = threadIdx.x & 31;
  int ty = threadIdx.x >> 5;
#pragma unroll
  for (int i = 0; i < 32; i += 8)
    tile[ty + i][tx] = in[(size_t)(by * 32 + ty + i) * C + bx * 32 + tx];
  __syncthreads();
#pragma unroll
  for (int i = 0; i < 32; i += 8)
    out[(size_t)(bx * 32 + ty + i) * R + by * 32 + tx] = f2bf(tile[tx][ty + i]);
}

// ---------------------------------------------------------------------------
// LayerNorm over D=1024, fp32 in -> bf16 out. One block per row.
// ---------------------------------------------------------------------------
__global__ __launch_bounds__(256) void ln_bf16(const float* __restrict__ x,
                                               const float* __restrict__ sc,
                                               const float* __restrict__ bi,
                                               unsigned short* __restrict__ y) {
  int row = blockIdx.x, tid = threadIdx.x, lane = tid & 63, wv = tid >> 6;
  const float* xr = x + (size_t)row * 1024;
  float4 v = *(const float4*)(xr + tid * 4);
  float s1 = v.x + v.y + v.z + v.w;
  float s2 = v.x * v.x + v.y * v.y + v.z * v.z + v.w * v.w;
#pragma unroll
  for (int o = 1; o < 64; o <<= 1) {
    s1 += __shfl_xor(s1, o);
    s2 += __shfl_xor(s2, o);
  }
  __shared__ float a1[4], a2[4];
  if (lane == 0) {
    a1[wv] = s1;
    a2[wv] = s2;
  }
  __syncthreads();
  s1 = a1[0] + a1[1] + a1[2] + a1[3];
  s2 = a2[0] + a2[1] + a2[2] + a2[3];
  float mu = s1 * (1.f / 1024.f);
  float var = s2 * (1.f / 1024.f) - mu * mu;
  float rs = rsqrtf(var + 1e-6f);
  int c = tid * 4;
  us4 o4;
  o4.x = f2bf((v.x - mu) * rs * sc[c + 0] + bi[c + 0]);
  o4.y = f2bf((v.y - mu) * rs * sc[c + 1] + bi[c + 1]);
  o4.z = f2bf((v.z - mu) * rs * sc[c + 2] + bi[c + 2]);
  o4.w = f2bf((v.w - mu) * rs * sc[c + 3] + bi[c + 3]);
  *(us4*)(y + (size_t)row * 1024 + c) = o4;
}

// ---------------------------------------------------------------------------
// bf16 GEMM, C = A[M][K] * B with Bt[N][K] storage. 128x128 tile, BK=32,
// 16x16x32 MFMA, reg-staged double-buffered LDS.
// EPI 0: fp32 store. EPI 1: bias+gelu -> bf16. EPI 2: res (+bias) -> fp32.
// ---------------------------------------------------------------------------
#define GBM 128
#define GBN 128
#define GBK 32

template <int EPI>
__global__ __launch_bounds__(256) void gemm_bt(
    const unsigned short* __restrict__ A, const unsigned short* __restrict__ Bt,
    const float* __restrict__ bias, const float* __restrict__ res,
    float* __restrict__ Cf, unsigned short* __restrict__ Cb, int M, int N,
    int K) {
  __shared__ unsigned short sA[2][GBM * GBK];
  __shared__ unsigned short sB[2][GBN * GBK];
  const int nbx = N / GBN;
  const int bx = blockIdx.x % nbx;
  const int by = blockIdx.x / nbx;
  const int tid = threadIdx.x;
  const int lane = tid & 63;
  const int wave = tid >> 6;
  const int wr = wave >> 1, wc = wave & 1;
  const int sr0 = tid >> 2;
  const int sc0 = (tid & 3) * 8;
  const unsigned short* Abase = A + (size_t)(by * GBM) * K;
  const unsigned short* Bbase = Bt + (size_t)(bx * GBN) * K;

  f32x4 acc[4][4];
#pragma unroll
  for (int m = 0; m < 4; ++m)
#pragma unroll
    for (int n = 0; n < 4; ++n) {
      f32x4 z = {0.f, 0.f, 0.f, 0.f};
      acc[m][n] = z;
    }

  const int KT = K / GBK;
  {
    short8 ra0 = *(const short8*)(Abase + (size_t)sr0 * K + sc0);
    short8 ra1 = *(const short8*)(Abase + (size_t)(sr0 + 64) * K + sc0);
    short8 rb0 = *(const short8*)(Bbase + (size_t)sr0 * K + sc0);
    short8 rb1 = *(const short8*)(Bbase + (size_t)(sr0 + 64) * K + sc0);
    *(short8*)&sA[0][sr0 * GBK + sc0] = ra0;
    *(short8*)&sA[0][(sr0 + 64) * GBK + sc0] = ra1;
    *(short8*)&sB[0][sr0 * GBK + sc0] = rb0;
    *(short8*)&sB[0][(sr0 + 64) * GBK + sc0] = rb1;
  }
  int cur = 0;
  const int arow = wr * 64 + (lane & 15);
  const int brow = wc * 64 + (lane & 15);
  const int koff = (lane >> 4) * 8;

  for (int kt = 0; kt < KT; ++kt) {
    __syncthreads();
    short8 na0, na1, nb0, nb1;
    if (kt + 1 < KT) {
      const unsigned short* An = Abase + (size_t)(kt + 1) * GBK;
      const unsigned short* Bn = Bbase + (size_t)(kt + 1) * GBK;
      na0 = *(const short8*)(An + (size_t)sr0 * K + sc0);
      na1 = *(const short8*)(An + (size_t)(sr0 + 64) * K + sc0);
      nb0 = *(const short8*)(Bn + (size_t)sr0 * K + sc0);
      nb1 = *(const short8*)(Bn + (size_t)(sr0 + 64) * K + sc0);
    }
    short8 af[4], bfv[4];
#pragma unroll
    for (int m = 0; m < 4; ++m)
      af[m] = *(const short8*)&sA[cur][(arow + m * 16) * GBK + koff];
#pragma unroll
    for (int n = 0; n < 4; ++n)
      bfv[n] = *(const short8*)&sB[cur][(brow + n * 16) * GBK + koff];
#pragma unroll
    for (int m = 0; m < 4; ++m)
#pragma unroll
      for (int n = 0; n < 4; ++n)
        acc[m][n] = __builtin_amdgcn_mfma_f32_16x16x32_bf16(af[m], bfv[n],
                                                            acc[m][n], 0, 0, 0);
    if (kt + 1 < KT) {
      __syncthreads();
      *(short8*)&sA[cur ^ 1][sr0 * GBK + sc0] = na0;
      *(short8*)&sA[cur ^ 1][(sr0 + 64) * GBK + sc0] = na1;
      *(short8*)&sB[cur ^ 1][sr0 * GBK + sc0] = nb0;
      *(short8*)&sB[cur ^ 1][(sr0 + 64) * GBK + sc0] = nb1;
      cur ^= 1;
    }
  }

  const int r0 = by * GBM + wr * 64;
  const int c0 = bx * GBN + wc * 64;
#pragma unroll
  for (int m = 0; m < 4; ++m) {
#pragma unroll
    for (int n = 0; n < 4; ++n) {
#pragma unroll
      for (int i = 0; i < 4; ++i) {
        int rr = r0 + m * 16 + ((lane >> 4) << 2) + i;
        int cc = c0 + n * 16 + (lane & 15);
        float vacc = acc[m][n][i];
        if (EPI == 0) {
          Cf[(size_t)rr * N + cc] = vacc;
        } else if (EPI == 1) {
          float t = vacc + bias[cc];
          Cb[(size_t)rr * N + cc] = f2bf(gelu_f(t));
        } else {
          float t = vacc + res[(size_t)rr * N + cc];
          if (bias != nullptr) t += bias[cc];
          Cf[(size_t)rr * N + cc] = t;
        }
      }
    }
  }
}

// ---------------------------------------------------------------------------
// Buckets + norms. One wave per (b,h,s) token.
// ---------------------------------------------------------------------------
__global__ __launch_bounds__(256) void bucket_kernel(
    const float* __restrict__ qk, const float* __restrict__ rot,
    float* __restrict__ norms, int* __restrict__ buckets) {
  __shared__ float rotl[64 * 64];
  __shared__ float xnl[4][64];
  int tid = threadIdx.x, lane = tid & 63, wv = tid >> 6;
  for (int i = tid; i < 4096; i += 256) rotl[i] = rot[i];
  __syncthreads();
  for (int it = 0; it < 8; ++it) {
    int g = (it * 4096 + blockIdx.x) * 4 + wv;
    int bh = g >> 12;
    int s = g & 4095;
    int b = bh >> 4, h = bh & 15;
    const float* xr = qk + ((size_t)(b * 4096 + s) * 1024 + h * 64);
    float x = xr[lane];
    float ss = x * x;
#pragma unroll
    for (int o = 1; o < 64; o <<= 1) ss += __shfl_xor(ss, o);
    float nrm = sqrtf(ss);
    float rn = 1.f / (nrm + 1e-6f);
    if (lane == 0) norms[g] = nrm;
    xnl[wv][lane] = x * rn;
    __syncthreads();
    int r_ = lane >> 5, m_ = lane & 31;
    float a = 0.f;
#pragma unroll 16
    for (int d = 0; d < 64; ++d) a += xnl[wv][d] * rotl[d * 64 + r_ * 32 + m_];
    float bv;
    int bi;
    if (a >= 0.f) {
      bv = a;
      bi = m_;
    } else {
      bv = -a;
      bi = m_ + 32;
    }
#pragma unroll
    for (int o = 16; o >= 1; o >>= 1) {
      float ov = __shfl_xor(bv, o);
      int oi = __shfl_xor(bi, o);
      if (ov > bv || (ov == bv && oi < bi)) {
        bv = ov;
        bi = oi;
      }
    }
    if (m_ == 0) buckets[((size_t)bh * 2 + r_) * 4096 + s] = bi;
    __syncthreads();
  }
}

// ---------------------------------------------------------------------------
// Parallel stable counting sort. One block (256 threads) per (b,h,r).
// Thread t owns tokens [t*16, t*16+16). Per-thread LDS histogram (row pad 65),
// column-exclusive prefix over threads, bucket-start scan, scattered write.
// ---------------------------------------------------------------------------
#define HSTR 65

__global__ __launch_bounds__(256) void sort_kernel(
    const int* __restrict__ buckets, int* __restrict__ order) {
  __shared__ unsigned int hist[256 * HSTR];
  __shared__ unsigned int bucketStart[64];
  const int bhr = blockIdx.x;
  const int t = threadIdx.x;
  const int* bk = buckets + (size_t)bhr * 4096;

  unsigned int* hrow = &hist[t * HSTR];
#pragma unroll
  for (int b = 0; b < 64; ++b) hrow[b] = 0u;

  int bks[16];
  {
    const int4* bp = (const int4*)(bk + t * 16);
#pragma unroll
    for (int j4 = 0; j4 < 4; ++j4) {
      int4 v = bp[j4];
      bks[j4 * 4 + 0] = v.x;
      bks[j4 * 4 + 1] = v.y;
      bks[j4 * 4 + 2] = v.z;
      bks[j4 * 4 + 3] = v.w;
    }
  }
  // cannot conflict with other threads: private row
#pragma unroll
  for (int j = 0; j < 16; ++j) hrow[bks[j]]++;
  __syncthreads();

  // column exclusive prefix over threads (lane b handles bucket b)
  if (t < 64) {
    unsigned int acc = 0;
    for (int t2 = 0; t2 < 256; ++t2) {
      unsigned int c = hist[t2 * HSTR + t];
      hist[t2 * HSTR + t] = acc;
      acc += c;
    }
    bucketStart[t] = acc;  // total for bucket t (scanned below)
  }
  __syncthreads();
  if (t == 0) {
    unsigned int acc = 0;
    for (int b = 0; b < 64; ++b) {
      unsigned int c = bucketStart[b];
      bucketStart[b] = acc;
      acc += c;
    }
  }
  __syncthreads();

  int* op = order + (size_t)bhr * 4096;
#pragma unroll
  for (int j = 0; j < 16; ++j) {
    int b = bks[j];
    unsigned int pos = bucketStart[b] + hrow[b];
    hrow[b]++;
    op[pos] = t * 16 + j;
  }
}

// ---------------------------------------------------------------------------
// MFMA LSH attention. One block per (b,h,r,chunk); 256 threads = 4 waves;
// wave wv owns q-rows [wv*32, wv*32+32). Per key chunk (own/prev/next):
// stage K (normalized bf16, stride 72) and V transposed (Vt[64][136]) in LDS,
// S = Q K^T via 16x16x32 MFMA, online softmax (fp32, running m/l per row),
// P -> bf16 in per-wave LDS, O += P V via MFMA. Epilogue: O/l, logsumexp.
// ---------------------------------------------------------------------------
#define KSTR 72
#define PSTR 136

__global__ __launch_bounds__(256, 2) void lsh_attn_mfma(
    const float* __restrict__ qk, const float* __restrict__ vv,
    const float* __restrict__ norms, const int* __restrict__ order,
    float* __restrict__ o, float* __restrict__ slog) {
  __shared__ unsigned short Kls[128 * KSTR];
  __shared__ unsigned short Vt[64 * PSTR];
  __shared__ unsigned short Pls[4][32 * PSTR];
  __shared__ int qtokL[128];
  __shared__ int btok[128];

  const int blk = blockIdx.x;
  const int c = blk & 31;
  const int bhr = blk >> 5;
  const int bh = bhr >> 1;
  const int h = bh & 15, b = bh >> 4;
  const int* ord = order + (size_t)bhr * 4096;
  const int tid = threadIdx.x, lane = tid & 63, wv = tid >> 6;
  const int l15 = lane & 15, lhi = lane >> 4;

  if (tid < 128) qtokL[tid] = ord[c * 128 + tid];
  __syncthreads();

  short8 qf[2][2];
#pragma unroll
  for (int mt = 0; mt < 2; ++mt) {
#pragma unroll
    for (int ks = 0; ks < 2; ++ks) {
      int row = wv * 32 + mt * 16 + l15;
      int tok = qtokL[row];
      const float* qp =
          qk + ((size_t)(b * 4096 + tok) * 1024 + h * 64) + ks * 32 + lhi * 8;
      float4 a0 = *(const float4*)qp;
      float4 a1 = *(const float4*)(qp + 4);
      short8 f;
      f[0] = (short)f2bf(a0.x);
      f[1] = (short)f2bf(a0.y);
      f[2] = (short)f2bf(a0.z);
      f[3] = (short)f2bf(a0.w);
      f[4] = (short)f2bf(a1.x);
      f[5] = (short)f2bf(a1.y);
      f[6] = (short)f2bf(a1.z);
      f[7] = (short)f2bf(a1.w);
      qf[mt][ks] = f;
    }
  }

  float mrun[2][4], lrun[2][4];
  f32x4 oacc[2][4];
#pragma unroll
  for (int mt = 0; mt < 2; ++mt)
#pragma unroll
    for (int i = 0; i < 4; ++i) {
      mrun[mt][i] = -1e30f;
      lrun[mt][i] = 0.f;
    }
#pragma unroll
  for (int mt = 0; mt < 2; ++mt)
#pragma unroll
    for (int n = 0; n < 4; ++n) {
      f32x4 z = {0.f, 0.f, 0.f, 0.f};
      oacc[mt][n] = z;
    }

  for (int st = 0; st < 3; ++st) {
    int kc = (st == 0) ? c : (st == 1) ? ((c + 31) & 31) : ((c + 1) & 31);
    __syncthreads();
    {
      int row = tid >> 1, half = tid & 1;
      int ktok = ord[kc * 128 + row];
      if (half == 0) btok[row] = ktok;
      float rn = 1.f / (norms[(size_t)bh * 4096 + ktok] + 1e-6f);
      const float* kp =
          qk + ((size_t)(b * 4096 + ktok) * 1024 + h * 64) + half * 32;
      const float* vp =
          vv + ((size_t)(b * 4096 + ktok) * 1024 + h * 64) + half * 32;
#pragma unroll
      for (int i = 0; i < 8; ++i) {
        float4 kk = ((const float4*)kp)[i];
        us4 kb;
        kb.x = f2bf(kk.x * rn);
        kb.y = f2bf(kk.y * rn);
        kb.z = f2bf(kk.z * rn);
        kb.w = f2bf(kk.w * rn);
        *(us4*)&Kls[row * KSTR + half * 32 + i * 4] = kb;
        float4 vw = ((const float4*)vp)[i];
        int d0 = half * 32 + i * 4;
        Vt[(d0 + 0) * PSTR + row] = f2bf(vw.x);
        Vt[(d0 + 1) * PSTR + row] = f2bf(vw.y);
        Vt[(d0 + 2) * PSTR + row] = f2bf(vw.z);
        Vt[(d0 + 3) * PSTR + row] = f2bf(vw.w);
      }
    }
    __syncthreads();

    f32x4 sacc[2][8];
#pragma unroll
    for (int mt = 0; mt < 2; ++mt)
#pragma unroll
      for (int n = 0; n < 8; ++n) {
        f32x4 z = {0.f, 0.f, 0.f, 0.f};
        sacc[mt][n] = z;
      }
#pragma unroll
    for (int ks = 0; ks < 2; ++ks) {
      short8 kf[8];
#pragma unroll
      for (int n = 0; n < 8; ++n)
        kf[n] = *(const short8*)&Kls[(n * 16 + l15) * KSTR + ks * 32 + lhi * 8];
#pragma unroll
      for (int mt = 0; mt < 2; ++mt)
#pragma unroll
        for (int n = 0; n < 8; ++n)
          sacc[mt][n] = __builtin_amdgcn_mfma_f32_16x16x32_bf16(
              qf[mt][ks], kf[n], sacc[mt][n], 0, 0, 0);
    }

    int ktA[8];
#pragma unroll
    for (int n = 0; n < 8; ++n) ktA[n] = btok[n * 16 + l15];
#pragma unroll
    for (int mt = 0; mt < 2; ++mt) {
#pragma unroll
      for (int i = 0; i < 4; ++i) {
        int qrow = wv * 32 + mt * 16 + lhi * 4 + i;
        int qt = qtokL[qrow];
        float sv[8];
        float mx = -1e30f;
#pragma unroll
        for (int n = 0; n < 8; ++n) {
          float s = sacc[mt][n][i] * 0.125f;
          if (ktA[n] == qt) s -= 1e5f;
          sv[n] = s;
          mx = fmaxf(mx, s);
        }
#pragma unroll
        for (int d = 1; d < 16; d <<= 1) mx = fmaxf(mx, __shfl_xor(mx, d));
        float mold = mrun[mt][i];
        float mnew = fmaxf(mold, mx);
        float scl = __expf(mold - mnew);
        lrun[mt][i] *= scl;
#pragma unroll
        for (int n = 0; n < 4; ++n) oacc[mt][n][i] *= scl;
        float ps = 0.f;
#pragma unroll
        for (int n = 0; n < 8; ++n) {
          float p = __expf(sv[n] - mnew);
          ps += p;
          Pls[wv][(mt * 16 + lhi * 4 + i) * PSTR + n * 16 + l15] = f2bf(p);
        }
#pragma unroll
        for (int d = 1; d < 16; d <<= 1) ps += __shfl_xor(ps, d);
        lrun[mt][i] = lrun[mt][i] + ps;
        mrun[mt][i] = mnew;
      }
    }

#pragma unroll
    for (int ks = 0; ks < 4; ++ks) {
      short8 pf[2];
#pragma unroll
      for (int mt = 0; mt < 2; ++mt)
        pf[mt] =
            *(const short8*)&Pls[wv][(mt * 16 + l15) * PSTR + ks * 32 + lhi * 8];
      short8 vfr[4];
#pragma unroll
      for (int n = 0; n < 4; ++n)
        vfr[n] = *(const short8*)&Vt[(n * 16 + l15) * PSTR + ks * 32 + lhi * 8];
#pragma unroll
      for (int mt = 0; mt < 2; ++mt)
#pragma unroll
        for (int n = 0; n < 4; ++n)
          oacc[mt][n] = __builtin_amdgcn_mfma_f32_16x16x32_bf16(
              pf[mt], vfr[n], oacc[mt][n], 0, 0, 0);
    }
  }

#pragma unroll
  for (int mt = 0; mt < 2; ++mt) {
#pragma unroll
    for (int i = 0; i < 4; ++i) {
      int qrow = wv * 32 + mt * 16 + lhi * 4 + i;
      int tok = qtokL[qrow];
      float l = lrun[mt][i];
      float invl = 1.f / l;
      if (l15 == 0) slog[(size_t)bhr * 4096 + tok] = logf(l) + mrun[mt][i];
      float* orow = o + ((size_t)bhr * 4096 + tok) * 64;
#pragma unroll
      for (int n = 0; n < 4; ++n) orow[n * 16 + l15] = oacc[mt][n][i] * invl;
    }
  }
}

// ---------------------------------------------------------------------------
// Combine hash rounds: w = softmax over r of slog; att = sum_r w_r * o_r.
// ---------------------------------------------------------------------------
__global__ __launch_bounds__(256) void combine_rounds(
    const float* __restrict__ o, const float* __restrict__ slog,
    unsigned short* __restrict__ att) {
  int g = blockIdx.x * 4 + (threadIdx.x >> 6);
  int lane = threadIdx.x & 63;
  int h = g & 15;
  int bs = g >> 4;
  int b = bs >> 12;
  int s = bs & 4095;
  size_t base = ((size_t)(b * 16 + h) * 2) * 4096 + s;
  size_t i0 = base;
  size_t i1 = base + 4096;
  float s0 = slog[i0], s1 = slog[i1];
  float mx = fmaxf(s0, s1);
  float e0 = __expf(s0 - mx), e1 = __expf(s1 - mx);
  float w0 = e0 / (e0 + e1);
  float w1 = 1.f - w0;
  float v0 = o[i0 * 64 + lane];
  float v1 = o[i1 * 64 + lane];
  att[(size_t)bs * 1024 + h * 64 + lane] = f2bf(w0 * v0 + w1 * v1);
}

// ---------------------------------------------------------------------------
extern "C" void kernel_launch(void* const* d_in, const int* in_sizes, int n_in,
                              void* d_out, int out_size, void* d_ws,
                              size_t ws_size, hipStream_t stream) {
  const float* inputs = (const float*)d_in[0];
  const float* ln1s = (const float*)d_in[1];
  const float* ln1b = (const float*)d_in[2];
  const float* wqk = (const float*)d_in[3];
  const float* wv = (const float*)d_in[4];
  const float* wout = (const float*)d_in[5];
  const float* rot = (const float*)d_in[6];
  const float* ln2s = (const float*)d_in[7];
  const float* ln2b = (const float*)d_in[8];
  const float* wm1 = (const float*)d_in[9];
  const float* bm1 = (const float*)d_in[10];
  const float* wm2 = (const float*)d_in[11];
  const float* bm2 = (const float*)d_in[12];

  char* w = (char*)d_ws;
  auto alloc = [&](size_t bytes) {
    char* p = w;
    w += (bytes + 255) & ~(size_t)255;
    return p;
  };
  unsigned short* wqk_bt = (unsigned short*)alloc(1024ull * 1024 * 2);
  unsigned short* wv_bt = (unsigned short*)alloc(1024ull * 1024 * 2);
  unsigned short* wout_bt = (unsigned short*)alloc(1024ull * 1024 * 2);
  unsigned short* wm1_bt = (unsigned short*)alloc(4096ull * 1024 * 2);
  unsigned short* wm2_bt = (unsigned short*)alloc(1024ull * 4096 * 2);
  unsigned short* bufA = (unsigned short*)alloc(8192ull * 1024 * 2);
  float* qkf = (float*)alloc(8192ull * 1024 * 4);
  float* vf = (float*)alloc(8192ull * 1024 * 4);  // later reused as x2
  float* norms = (float*)alloc(2ull * 16 * 4096 * 4);
  int* buckets = (int*)alloc(64ull * 4096 * 4);
  int* order = (int*)alloc(64ull * 4096 * 4);
  float* obuf = (float*)alloc(64ull * 4096 * 64 * 4);  // reused as h1 (bf16)
  float* slogb = (float*)alloc(64ull * 4096 * 4);
  float* x2 = vf;
  unsigned short* h1 = (unsigned short*)obuf;

  transpose_cast<<<32 * 32, 256, 0, stream>>>(wqk, wqk_bt, 1024, 1024);
  transpose_cast<<<32 * 32, 256, 0, stream>>>(wv, wv_bt, 1024, 1024);
  transpose_cast<<<32 * 32, 256, 0, stream>>>(wout, wout_bt, 1024, 1024);
  transpose_cast<<<32 * 128, 256, 0, stream>>>(wm1, wm1_bt, 1024, 4096);
  transpose_cast<<<128 * 32, 256, 0, stream>>>(wm2, wm2_bt, 4096, 1024);

  ln_bf16<<<8192, 256, 0, stream>>>(inputs, ln1s, ln1b, bufA);

  gemm_bt<0><<<64 * 8, 256, 0, stream>>>(bufA, wqk_bt, nullptr, nullptr, qkf,
                                         nullptr, 8192, 1024, 1024);
  gemm_bt<0><<<64 * 8, 256, 0, stream>>>(bufA, wv_bt, nullptr, nullptr, vf,
                                         nullptr, 8192, 1024, 1024);

  bucket_kernel<<<4096, 256, 0, stream>>>(qkf, rot, norms, buckets);
  sort_kernel<<<64, 256, 0, stream>>>(buckets, order);
  lsh_attn_mfma<<<2048, 256, 0, stream>>>(qkf, vf, norms, order, obuf, slogb);
  combine_rounds<<<32768, 256, 0, stream>>>(obuf, slogb, bufA);

  gemm_bt<2><<<64 * 8, 256, 0, stream>>>(bufA, wout_bt, nullptr, inputs, x2,
                                         nullptr, 8192, 1024, 1024);
  ln_bf16<<<8192, 256, 0, stream>>>(x2, ln2s, ln2b, bufA);
  gemm_bt<1><<<64 * 32, 256, 0, stream>>>(bufA, wm1_bt, bm1, nullptr, nullptr,
                                          h1, 8192, 4096, 1024);
  gemm_bt<2><<<64 * 8, 256, 0, stream>>>(h1, wm2_bt, bm2, x2, (float*)d_out,
                                         nullptr, 8192, 1024, 4096);
}

// Round 5
// 556.341 us; speedup vs baseline: 2.4883x; 1.0174x over previous
//
#include <hip/hip_runtime.h>
#include <hip/hip_bf16.h>

// ---------------------------------------------------------------------------
// ReformerBlockPreLN on MI355X — round 4: fix global_load_lds staging coverage
// (2 loads/lane/matrix; round-3 issued 1 -> half the tile was garbage)
// B=2 S=4096 D=1024 H=16 DH=64 R=2 NBUCK=64 CHUNK=128 MLP=4096
// ---------------------------------------------------------------------------

typedef short short8 __attribute__((ext_vector_type(8)));
typedef float f32x4 __attribute__((ext_vector_type(4)));
typedef unsigned short us4 __attribute__((ext_vector_type(4)));

__device__ __forceinline__ unsigned short f2bf(float f) {
  unsigned u = __builtin_bit_cast(unsigned, f);
  u += 0x7FFFu + ((u >> 16) & 1u);
  return (unsigned short)(u >> 16);
}

__device__ __forceinline__ float bf2f(unsigned short u) {
  return __builtin_bit_cast(float, ((unsigned)u) << 16);
}

__device__ __forceinline__ float gelu_f(float x) {
  float x3 = x * x * x;
  float t = tanhf(0.7978845608028654f * (x + 0.044715f * x3));
  return 0.5f * x * (1.0f + t);
}

__device__ __forceinline__ void load_lds16(const void* g, void* l) {
  __builtin_amdgcn_global_load_lds(
      (const __attribute__((address_space(1))) unsigned int*)g,
      (__attribute__((address_space(3))) unsigned int*)l, 16, 0, 0);
}

// ---------------------------------------------------------------------------
// transpose + cast fp32 [R][C] -> bf16 [C][R]
// ---------------------------------------------------------------------------
__global__ __launch_bounds__(256) void transpose_cast(
    const float* __restrict__ in, unsigned short* __restrict__ out, int R,
    int C) {
  __shared__ float tile[32][33];
  int ctiles = C >> 5;
  int bx = blockIdx.x % ctiles;
  int by = blockIdx.x / ctiles;
  int tx = threadIdx.x & 31;
  int ty = threadIdx.x >> 5;
#pragma unroll
  for (int i = 0; i < 32; i += 8)
    tile[ty + i][tx] = in[(size_t)(by * 32 + ty + i) * C + bx * 32 + tx];
  __syncthreads();
#pragma unroll
  for (int i = 0; i < 32; i += 8)
    out[(size_t)(bx * 32 + ty + i) * R + by * 32 + tx] = f2bf(tile[tx][ty + i]);
}

// ---------------------------------------------------------------------------
// LayerNorm over D=1024, fp32 in -> bf16 out. One block per row.
// ---------------------------------------------------------------------------
__global__ __launch_bounds__(256) void ln_bf16(const float* __restrict__ x,
                                               const float* __restrict__ sc,
                                               const float* __restrict__ bi,
                                               unsigned short* __restrict__ y) {
  int row = blockIdx.x, tid = threadIdx.x, lane = tid & 63, wv = tid >> 6;
  const float* xr = x + (size_t)row * 1024;
  float4 v = *(const float4*)(xr + tid * 4);
  float s1 = v.x + v.y + v.z + v.w;
  float s2 = v.x * v.x + v.y * v.y + v.z * v.z + v.w * v.w;
#pragma unroll
  for (int o = 1; o < 64; o <<= 1) {
    s1 += __shfl_xor(s1, o);
    s2 += __shfl_xor(s2, o);
  }
  __shared__ float a1[4], a2[4];
  if (lane == 0) {
    a1[wv] = s1;
    a2[wv] = s2;
  }
  __syncthreads();
  s1 = a1[0] + a1[1] + a1[2] + a1[3];
  s2 = a2[0] + a2[1] + a2[2] + a2[3];
  float mu = s1 * (1.f / 1024.f);
  float var = s2 * (1.f / 1024.f) - mu * mu;
  float rs = rsqrtf(var + 1e-6f);
  int c = tid * 4;
  us4 o4;
  o4.x = f2bf((v.x - mu) * rs * sc[c + 0] + bi[c + 0]);
  o4.y = f2bf((v.y - mu) * rs * sc[c + 1] + bi[c + 1]);
  o4.z = f2bf((v.z - mu) * rs * sc[c + 2] + bi[c + 2]);
  o4.w = f2bf((v.w - mu) * rs * sc[c + 3] + bi[c + 3]);
  *(us4*)(y + (size_t)row * 1024 + c) = o4;
}

// ---------------------------------------------------------------------------
// bf16 GEMM, C = A[M][K] * Bt[N][K]. 128x128 tile, BK=32, 16x16x32 MFMA.
// global_load_lds direct staging (width 16, 2 loads/lane/matrix),
// double-buffered LDS, 1 barrier per K-step.
// EPI 1: bias+gelu -> bf16. EPI 2: res (+bias) -> fp32.
// EPI 3: fp32 + bf16 dual store. EPI 4: bf16 store.
// ---------------------------------------------------------------------------
#define GBM 128
#define GBN 128
#define GBK 32

template <int EPI>
__global__ __launch_bounds__(256) void gemm_bt(
    const unsigned short* __restrict__ A, const unsigned short* __restrict__ Bt,
    const float* __restrict__ bias, const float* __restrict__ res,
    float* __restrict__ Cf, unsigned short* __restrict__ Cb, int M, int N,
    int K) {
  __shared__ unsigned short sA[2][GBM * GBK];
  __shared__ unsigned short sB[2][GBN * GBK];
  const int nbx = N / GBN;
  const int bx = blockIdx.x % nbx;
  const int by = blockIdx.x / nbx;
  const int tid = threadIdx.x;
  const int lane = tid & 63;
  const int wave = tid >> 6;
  const int wr = wave >> 1, wc = wave & 1;
  const unsigned short* Abase = A + (size_t)(by * GBM) * K;
  const unsigned short* Bbase = Bt + (size_t)(bx * GBN) * K;

  // staging: wave w covers rows [w*32, w*32+32). Lane l -> row w*32+(l>>2)
  // (+16 for the second load), col (l&3)*8. LDS linear [row][32]:
  // byte offset (l>>2)*64+(l&3)*16 == 16*l  => matches HW base+lane*16.
  const int strow = wave * 32 + (lane >> 2);
  const int stcol = (lane & 3) * 8;
  const unsigned short* Ag = Abase + (size_t)strow * K + stcol;
  const unsigned short* Bg = Bbase + (size_t)strow * K + stcol;
  const int ldsoff = wave * 32 * GBK;       // elements
  const int ldsoff2 = ldsoff + 16 * GBK;    // rows +16

  f32x4 acc[4][4];
#pragma unroll
  for (int m = 0; m < 4; ++m)
#pragma unroll
    for (int n = 0; n < 4; ++n) {
      f32x4 z = {0.f, 0.f, 0.f, 0.f};
      acc[m][n] = z;
    }

  const int KT = K / GBK;
  // prologue: stage k-tile 0 into buffer 0
  load_lds16(Ag, &sA[0][ldsoff]);
  load_lds16(Ag + (size_t)16 * K, &sA[0][ldsoff2]);
  load_lds16(Bg, &sB[0][ldsoff]);
  load_lds16(Bg + (size_t)16 * K, &sB[0][ldsoff2]);
  __syncthreads();

  int cur = 0;
  const int arow = wr * 64 + (lane & 15);
  const int brow = wc * 64 + (lane & 15);
  const int koff = (lane >> 4) * 8;

  for (int kt = 0; kt < KT; ++kt) {
    if (kt + 1 < KT) {
      const unsigned short* An = Ag + (size_t)(kt + 1) * GBK;
      const unsigned short* Bn = Bg + (size_t)(kt + 1) * GBK;
      load_lds16(An, &sA[cur ^ 1][ldsoff]);
      load_lds16(An + (size_t)16 * K, &sA[cur ^ 1][ldsoff2]);
      load_lds16(Bn, &sB[cur ^ 1][ldsoff]);
      load_lds16(Bn + (size_t)16 * K, &sB[cur ^ 1][ldsoff2]);
    }
    short8 af[4], bfv[4];
#pragma unroll
    for (int m = 0; m < 4; ++m)
      af[m] = *(const short8*)&sA[cur][(arow + m * 16) * GBK + koff];
#pragma unroll
    for (int n = 0; n < 4; ++n)
      bfv[n] = *(const short8*)&sB[cur][(brow + n * 16) * GBK + koff];
#pragma unroll
    for (int m = 0; m < 4; ++m)
#pragma unroll
      for (int n = 0; n < 4; ++n)
        acc[m][n] = __builtin_amdgcn_mfma_f32_16x16x32_bf16(af[m], bfv[n],
                                                            acc[m][n], 0, 0, 0);
    __syncthreads();  // drains vmcnt (staged tile ready) + lgkm (reads done)
    cur ^= 1;
  }

  const int r0 = by * GBM + wr * 64;
  const int c0 = bx * GBN + wc * 64;
#pragma unroll
  for (int m = 0; m < 4; ++m) {
#pragma unroll
    for (int n = 0; n < 4; ++n) {
#pragma unroll
      for (int i = 0; i < 4; ++i) {
        int rr = r0 + m * 16 + ((lane >> 4) << 2) + i;
        int cc = c0 + n * 16 + (lane & 15);
        float vacc = acc[m][n][i];
        if (EPI == 1) {
          float t = vacc + bias[cc];
          Cb[(size_t)rr * N + cc] = f2bf(gelu_f(t));
        } else if (EPI == 2) {
          float t = vacc + res[(size_t)rr * N + cc];
          if (bias != nullptr) t += bias[cc];
          Cf[(size_t)rr * N + cc] = t;
        } else if (EPI == 3) {
          Cf[(size_t)rr * N + cc] = vacc;
          Cb[(size_t)rr * N + cc] = f2bf(vacc);
        } else if (EPI == 4) {
          Cb[(size_t)rr * N + cc] = f2bf(vacc);
        }
      }
    }
  }
}

// ---------------------------------------------------------------------------
// Buckets + normalized-K pack. One wave per (b,h,s) token.
// Writes knb = bf16(qk/(|qk|+1e-6)) and buckets.
// ---------------------------------------------------------------------------
__global__ __launch_bounds__(256) void bucket_kernel(
    const float* __restrict__ qk, const float* __restrict__ rot,
    unsigned short* __restrict__ knb, int* __restrict__ buckets) {
  __shared__ float rotl[64 * 64];
  __shared__ float xnl[4][64];
  int tid = threadIdx.x, lane = tid & 63, wv = tid >> 6;
  for (int i = tid; i < 4096; i += 256) rotl[i] = rot[i];
  __syncthreads();
  for (int it = 0; it < 8; ++it) {
    int g = (it * 4096 + blockIdx.x) * 4 + wv;
    int bh = g >> 12;
    int s = g & 4095;
    int b = bh >> 4, h = bh & 15;
    size_t rowoff = (size_t)(b * 4096 + s) * 1024 + h * 64;
    float x = qk[rowoff + lane];
    float ss = x * x;
#pragma unroll
    for (int o = 1; o < 64; o <<= 1) ss += __shfl_xor(ss, o);
    float rn = 1.f / (sqrtf(ss) + 1e-6f);
    float xn = x * rn;
    knb[rowoff + lane] = f2bf(xn);
    xnl[wv][lane] = xn;
    __syncthreads();
    int r_ = lane >> 5, m_ = lane & 31;
    float a = 0.f;
#pragma unroll 16
    for (int d = 0; d < 64; ++d) a += xnl[wv][d] * rotl[d * 64 + r_ * 32 + m_];
    float bv;
    int bi;
    if (a >= 0.f) {
      bv = a;
      bi = m_;
    } else {
      bv = -a;
      bi = m_ + 32;
    }
#pragma unroll
    for (int o = 16; o >= 1; o >>= 1) {
      float ov = __shfl_xor(bv, o);
      int oi = __shfl_xor(bi, o);
      if (ov > bv || (ov == bv && oi < bi)) {
        bv = ov;
        bi = oi;
      }
    }
    if (m_ == 0) buckets[((size_t)bh * 2 + r_) * 4096 + s] = bi;
    __syncthreads();
  }
}

// ---------------------------------------------------------------------------
// Parallel stable counting sort. One block (256 threads) per (b,h,r).
// ---------------------------------------------------------------------------
#define HSTR 65

__global__ __launch_bounds__(256) void sort_kernel(
    const int* __restrict__ buckets, int* __restrict__ order) {
  __shared__ unsigned int hist[256 * HSTR];
  __shared__ unsigned int bucketStart[64];
  const int bhr = blockIdx.x;
  const int t = threadIdx.x;
  const int* bk = buckets + (size_t)bhr * 4096;

  unsigned int* hrow = &hist[t * HSTR];
#pragma unroll
  for (int b = 0; b < 64; ++b) hrow[b] = 0u;

  int bks[16];
  {
    const int4* bp = (const int4*)(bk + t * 16);
#pragma unroll
    for (int j4 = 0; j4 < 4; ++j4) {
      int4 v = bp[j4];
      bks[j4 * 4 + 0] = v.x;
      bks[j4 * 4 + 1] = v.y;
      bks[j4 * 4 + 2] = v.z;
      bks[j4 * 4 + 3] = v.w;
    }
  }
#pragma unroll
  for (int j = 0; j < 16; ++j) hrow[bks[j]]++;
  __syncthreads();

  if (t < 64) {
    unsigned int acc = 0;
    for (int t2 = 0; t2 < 256; ++t2) {
      unsigned int c = hist[t2 * HSTR + t];
      hist[t2 * HSTR + t] = acc;
      acc += c;
    }
    bucketStart[t] = acc;
  }
  __syncthreads();
  if (t == 0) {
    unsigned int acc = 0;
    for (int b = 0; b < 64; ++b) {
      unsigned int c = bucketStart[b];
      bucketStart[b] = acc;
      acc += c;
    }
  }
  __syncthreads();

  int* op = order + (size_t)bhr * 4096;
#pragma unroll
  for (int j = 0; j < 16; ++j) {
    int b = bks[j];
    unsigned int pos = bucketStart[b] + hrow[b];
    hrow[b]++;
    op[pos] = t * 16 + j;
  }
}

// ---------------------------------------------------------------------------
// MFMA LSH attention, all-bf16 data path. One block per (b,h,r,chunk);
// 4 waves, wave owns 32 q-rows. Stages bf16 K (pre-normalized) and V
// (transposed) per key chunk; S = Q K^T; online softmax; O += P V.
// Writes bf16 o and fp32 logsumexp.
// ---------------------------------------------------------------------------
#define KSTR 72
#define PSTR 136

__global__ __launch_bounds__(256, 2) void lsh_attn_mfma(
    const unsigned short* __restrict__ qb, const unsigned short* __restrict__ knb,
    const unsigned short* __restrict__ vb, const int* __restrict__ order,
    unsigned short* __restrict__ ob, float* __restrict__ slog) {
  __shared__ unsigned short Kls[128 * KSTR];
  __shared__ unsigned short Vt[64 * PSTR];
  __shared__ unsigned short Pls[4][32 * PSTR];
  __shared__ int qtokL[128];
  __shared__ int btok[128];

  const int blk = blockIdx.x;
  const int c = blk & 31;
  const int bhr = blk >> 5;
  const int bh = bhr >> 1;
  const int h = bh & 15, b = bh >> 4;
  const int* ord = order + (size_t)bhr * 4096;
  const int tid = threadIdx.x, lane = tid & 63, wv = tid >> 6;
  const int l15 = lane & 15, lhi = lane >> 4;

  if (tid < 128) qtokL[tid] = ord[c * 128 + tid];
  __syncthreads();

  short8 qf[2][2];
#pragma unroll
  for (int mt = 0; mt < 2; ++mt) {
#pragma unroll
    for (int ks = 0; ks < 2; ++ks) {
      int tok = qtokL[wv * 32 + mt * 16 + l15];
      qf[mt][ks] = *(const short8*)(qb + (size_t)(b * 4096 + tok) * 1024 +
                                    h * 64 + ks * 32 + lhi * 8);
    }
  }

  float mrun[2][4], lrun[2][4];
  f32x4 oacc[2][4];
#pragma unroll
  for (int mt = 0; mt < 2; ++mt)
#pragma unroll
    for (int i = 0; i < 4; ++i) {
      mrun[mt][i] = -1e30f;
      lrun[mt][i] = 0.f;
    }
#pragma unroll
  for (int mt = 0; mt < 2; ++mt)
#pragma unroll
    for (int n = 0; n < 4; ++n) {
      f32x4 z = {0.f, 0.f, 0.f, 0.f};
      oacc[mt][n] = z;
    }

  for (int st = 0; st < 3; ++st) {
    int kc = (st == 0) ? c : (st == 1) ? ((c + 31) & 31) : ((c + 1) & 31);
    __syncthreads();
    {
      int row = tid >> 1, half = tid & 1;
      int ktok = ord[kc * 128 + row];
      if (half == 0) btok[row] = ktok;
      size_t rowoff = (size_t)(b * 4096 + ktok) * 1024 + h * 64 + half * 32;
      const short8* kp = (const short8*)(knb + rowoff);
      const short8* vp = (const short8*)(vb + rowoff);
#pragma unroll
      for (int i = 0; i < 4; ++i)
        *(short8*)&Kls[row * KSTR + half * 32 + i * 8] = kp[i];
#pragma unroll
      for (int i = 0; i < 4; ++i) {
        short8 vw = vp[i];
        int d0 = half * 32 + i * 8;
#pragma unroll
        for (int j = 0; j < 8; ++j)
          Vt[(d0 + j) * PSTR + row] = (unsigned short)vw[j];
      }
    }
    __syncthreads();

    f32x4 sacc[2][8];
#pragma unroll
    for (int mt = 0; mt < 2; ++mt)
#pragma unroll
      for (int n = 0; n < 8; ++n) {
        f32x4 z = {0.f, 0.f, 0.f, 0.f};
        sacc[mt][n] = z;
      }
#pragma unroll
    for (int ks = 0; ks < 2; ++ks) {
      short8 kf[8];
#pragma unroll
      for (int n = 0; n < 8; ++n)
        kf[n] = *(const short8*)&Kls[(n * 16 + l15) * KSTR + ks * 32 + lhi * 8];
#pragma unroll
      for (int mt = 0; mt < 2; ++mt)
#pragma unroll
        for (int n = 0; n < 8; ++n)
          sacc[mt][n] = __builtin_amdgcn_mfma_f32_16x16x32_bf16(
              qf[mt][ks], kf[n], sacc[mt][n], 0, 0, 0);
    }

    int ktA[8];
#pragma unroll
    for (int n = 0; n < 8; ++n) ktA[n] = btok[n * 16 + l15];
#pragma unroll
    for (int mt = 0; mt < 2; ++mt) {
#pragma unroll
      for (int i = 0; i < 4; ++i) {
        int qrow = wv * 32 + mt * 16 + lhi * 4 + i;
        int qt = qtokL[qrow];
        float sv[8];
        float mx = -1e30f;
#pragma unroll
        for (int n = 0; n < 8; ++n) {
          float s = sacc[mt][n][i] * 0.125f;
          if (ktA[n] == qt) s -= 1e5f;
          sv[n] = s;
          mx = fmaxf(mx, s);
        }
#pragma unroll
        for (int d = 1; d < 16; d <<= 1) mx = fmaxf(mx, __shfl_xor(mx, d));
        float mold = mrun[mt][i];
        float mnew = fmaxf(mold, mx);
        float scl = __expf(mold - mnew);
        lrun[mt][i] *= scl;
#pragma unroll
        for (int n = 0; n < 4; ++n) oacc[mt][n][i] *= scl;
        float ps = 0.f;
#pragma unroll
        for (int n = 0; n < 8; ++n) {
          float p = __expf(sv[n] - mnew);
          ps += p;
          Pls[wv][(mt * 16 + lhi * 4 + i) * PSTR + n * 16 + l15] = f2bf(p);
        }
#pragma unroll
        for (int d = 1; d < 16; d <<= 1) ps += __shfl_xor(ps, d);
        lrun[mt][i] = lrun[mt][i] + ps;
        mrun[mt][i] = mnew;
      }
    }

#pragma unroll
    for (int ks = 0; ks < 4; ++ks) {
      short8 pf[2];
#pragma unroll
      for (int mt = 0; mt < 2; ++mt)
        pf[mt] =
            *(const short8*)&Pls[wv][(mt * 16 + l15) * PSTR + ks * 32 + lhi * 8];
      short8 vfr[4];
#pragma unroll
      for (int n = 0; n < 4; ++n)
        vfr[n] = *(const short8*)&Vt[(n * 16 + l15) * PSTR + ks * 32 + lhi * 8];
#pragma unroll
      for (int mt = 0; mt < 2; ++mt)
#pragma unroll
        for (int n = 0; n < 4; ++n)
          oacc[mt][n] = __builtin_amdgcn_mfma_f32_16x16x32_bf16(
              pf[mt], vfr[n], oacc[mt][n], 0, 0, 0);
    }
  }

#pragma unroll
  for (int mt = 0; mt < 2; ++mt) {
#pragma unroll
    for (int i = 0; i < 4; ++i) {
      int qrow = wv * 32 + mt * 16 + lhi * 4 + i;
      int tok = qtokL[qrow];
      float l = lrun[mt][i];
      float invl = 1.f / l;
      if (l15 == 0) slog[(size_t)bhr * 4096 + tok] = logf(l) + mrun[mt][i];
      unsigned short* orow = ob + ((size_t)bhr * 4096 + tok) * 64;
#pragma unroll
      for (int n = 0; n < 4; ++n)
        orow[n * 16 + l15] = f2bf(oacc[mt][n][i] * invl);
    }
  }
}

// ---------------------------------------------------------------------------
// Combine hash rounds: w = softmax over r of slog; att = sum_r w_r * o_r.
// ---------------------------------------------------------------------------
__global__ __launch_bounds__(256) void combine_rounds(
    const unsigned short* __restrict__ ob, const float* __restrict__ slog,
    unsigned short* __restrict__ att) {
  int g = blockIdx.x * 4 + (threadIdx.x >> 6);
  int lane = threadIdx.x & 63;
  int h = g & 15;
  int bs = g >> 4;
  int b = bs >> 12;
  int s = bs & 4095;
  size_t base = ((size_t)(b * 16 + h) * 2) * 4096 + s;
  size_t i0 = base;
  size_t i1 = base + 4096;
  float s0 = slog[i0], s1 = slog[i1];
  float mx = fmaxf(s0, s1);
  float e0 = __expf(s0 - mx), e1 = __expf(s1 - mx);
  float w0 = e0 / (e0 + e1);
  float w1 = 1.f - w0;
  float v0 = bf2f(ob[i0 * 64 + lane]);
  float v1 = bf2f(ob[i1 * 64 + lane]);
  att[(size_t)bs * 1024 + h * 64 + lane] = f2bf(w0 * v0 + w1 * v1);
}

// ---------------------------------------------------------------------------
extern "C" void kernel_launch(void* const* d_in, const int* in_sizes, int n_in,
                              void* d_out, int out_size, void* d_ws,
                              size_t ws_size, hipStream_t stream) {
  const float* inputs = (const float*)d_in[0];
  const float* ln1s = (const float*)d_in[1];
  const float* ln1b = (const float*)d_in[2];
  const float* wqk = (const float*)d_in[3];
  const float* wv = (const float*)d_in[4];
  const float* wout = (const float*)d_in[5];
  const float* rot = (const float*)d_in[6];
  const float* ln2s = (const float*)d_in[7];
  const float* ln2b = (const float*)d_in[8];
  const float* wm1 = (const float*)d_in[9];
  const float* bm1 = (const float*)d_in[10];
  const float* wm2 = (const float*)d_in[11];
  const float* bm2 = (const float*)d_in[12];

  char* w = (char*)d_ws;
  auto alloc = [&](size_t bytes) {
    char* p = w;
    w += (bytes + 255) & ~(size_t)255;
    return p;
  };
  unsigned short* wqk_bt = (unsigned short*)alloc(1024ull * 1024 * 2);
  unsigned short* wv_bt = (unsigned short*)alloc(1024ull * 1024 * 2);
  unsigned short* wout_bt = (unsigned short*)alloc(1024ull * 1024 * 2);
  unsigned short* wm1_bt = (unsigned short*)alloc(4096ull * 1024 * 2);
  unsigned short* wm2_bt = (unsigned short*)alloc(1024ull * 4096 * 2);
  unsigned short* bufA = (unsigned short*)alloc(8192ull * 1024 * 2);
  float* qkf = (float*)alloc(8192ull * 1024 * 4);  // dead after buckets -> x2
  unsigned short* qb = (unsigned short*)alloc(8192ull * 1024 * 2);
  unsigned short* knb = (unsigned short*)alloc(8192ull * 1024 * 2);
  unsigned short* vb = (unsigned short*)alloc(8192ull * 1024 * 2);
  int* buckets = (int*)alloc(64ull * 4096 * 4);
  int* order = (int*)alloc(64ull * 4096 * 4);
  unsigned short* big =
      (unsigned short*)alloc(8192ull * 4096 * 2);  // obuf then h1
  float* slogb = (float*)alloc(64ull * 4096 * 4);
  float* x2 = qkf;
  unsigned short* obuf = big;
  unsigned short* h1 = big;

  transpose_cast<<<32 * 32, 256, 0, stream>>>(wqk, wqk_bt, 1024, 1024);
  transpose_cast<<<32 * 32, 256, 0, stream>>>(wv, wv_bt, 1024, 1024);
  transpose_cast<<<32 * 32, 256, 0, stream>>>(wout, wout_bt, 1024, 1024);
  transpose_cast<<<32 * 128, 256, 0, stream>>>(wm1, wm1_bt, 1024, 4096);
  transpose_cast<<<128 * 32, 256, 0, stream>>>(wm2, wm2_bt, 4096, 1024);

  ln_bf16<<<8192, 256, 0, stream>>>(inputs, ln1s, ln1b, bufA);

  // qk: fp32 (for buckets) + bf16 (for attention); v: bf16 only
  gemm_bt<3><<<64 * 8, 256, 0, stream>>>(bufA, wqk_bt, nullptr, nullptr, qkf,
                                         qb, 8192, 1024, 1024);
  gemm_bt<4><<<64 * 8, 256, 0, stream>>>(bufA, wv_bt, nullptr, nullptr, nullptr,
                                         vb, 8192, 1024, 1024);

  bucket_kernel<<<4096, 256, 0, stream>>>(qkf, rot, knb, buckets);
  sort_kernel<<<64, 256, 0, stream>>>(buckets, order);
  lsh_attn_mfma<<<2048, 256, 0, stream>>>(qb, knb, vb, order, obuf, slogb);
  combine_rounds<<<32768, 256, 0, stream>>>(obuf, slogb, bufA);

  gemm_bt<2><<<64 * 8, 256, 0, stream>>>(bufA, wout_bt, nullptr, inputs, x2,
                                         nullptr, 8192, 1024, 1024);
  ln_bf16<<<8192, 256, 0, stream>>>(x2, ln2s, ln2b, bufA);
  gemm_bt<1><<<64 * 32, 256, 0, stream>>>(bufA, wm1_bt, bm1, nullptr, nullptr,
                                          h1, 8192, 4096, 1024);
  gemm_bt<2><<<64 * 8, 256, 0, stream>>>(h1, wm2_bt, bm2, x2, (float*)d_out,
                                         nullptr, 8192, 1024, 4096);
}

// Round 6
// 537.360 us; speedup vs baseline: 2.5761x; 1.0353x over previous
//
#include <hip/hip_runtime.h>
#include <hip/hip_bf16.h>

// ---------------------------------------------------------------------------
// ReformerBlockPreLN on MI355X — round 5: chunked XCD swizzle (T1) on GEMMs
// + attention (A-stripe stays on one XCD's L2; kills cross-XCD re-fetch)
// B=2 S=4096 D=1024 H=16 DH=64 R=2 NBUCK=64 CHUNK=128 MLP=4096
// ---------------------------------------------------------------------------

typedef short short8 __attribute__((ext_vector_type(8)));
typedef float f32x4 __attribute__((ext_vector_type(4)));
typedef unsigned short us4 __attribute__((ext_vector_type(4)));

__device__ __forceinline__ unsigned short f2bf(float f) {
  unsigned u = __builtin_bit_cast(unsigned, f);
  u += 0x7FFFu + ((u >> 16) & 1u);
  return (unsigned short)(u >> 16);
}

__device__ __forceinline__ float bf2f(unsigned short u) {
  return __builtin_bit_cast(float, ((unsigned)u) << 16);
}

__device__ __forceinline__ float gelu_f(float x) {
  float x3 = x * x * x;
  float t = tanhf(0.7978845608028654f * (x + 0.044715f * x3));
  return 0.5f * x * (1.0f + t);
}

__device__ __forceinline__ void load_lds16(const void* g, void* l) {
  __builtin_amdgcn_global_load_lds(
      (const __attribute__((address_space(1))) unsigned int*)g,
      (__attribute__((address_space(3))) unsigned int*)l, 16, 0, 0);
}

// ---------------------------------------------------------------------------
// transpose + cast fp32 [R][C] -> bf16 [C][R]
// ---------------------------------------------------------------------------
__global__ __launch_bounds__(256) void transpose_cast(
    const float* __restrict__ in, unsigned short* __restrict__ out, int R,
    int C) {
  __shared__ float tile[32][33];
  int ctiles = C >> 5;
  int bx = blockIdx.x % ctiles;
  int by = blockIdx.x / ctiles;
  int tx = threadIdx.x & 31;
  int ty = threadIdx.x >> 5;
#pragma unroll
  for (int i = 0; i < 32; i += 8)
    tile[ty + i][tx] = in[(size_t)(by * 32 + ty + i) * C + bx * 32 + tx];
  __syncthreads();
#pragma unroll
  for (int i = 0; i < 32; i += 8)
    out[(size_t)(bx * 32 + ty + i) * R + by * 32 + tx] = f2bf(tile[tx][ty + i]);
}

// ---------------------------------------------------------------------------
// LayerNorm over D=1024, fp32 in -> bf16 out. One block per row.
// ---------------------------------------------------------------------------
__global__ __launch_bounds__(256) void ln_bf16(const float* __restrict__ x,
                                               const float* __restrict__ sc,
                                               const float* __restrict__ bi,
                                               unsigned short* __restrict__ y) {
  int row = blockIdx.x, tid = threadIdx.x, lane = tid & 63, wv = tid >> 6;
  const float* xr = x + (size_t)row * 1024;
  float4 v = *(const float4*)(xr + tid * 4);
  float s1 = v.x + v.y + v.z + v.w;
  float s2 = v.x * v.x + v.y * v.y + v.z * v.z + v.w * v.w;
#pragma unroll
  for (int o = 1; o < 64; o <<= 1) {
    s1 += __shfl_xor(s1, o);
    s2 += __shfl_xor(s2, o);
  }
  __shared__ float a1[4], a2[4];
  if (lane == 0) {
    a1[wv] = s1;
    a2[wv] = s2;
  }
  __syncthreads();
  s1 = a1[0] + a1[1] + a1[2] + a1[3];
  s2 = a2[0] + a2[1] + a2[2] + a2[3];
  float mu = s1 * (1.f / 1024.f);
  float var = s2 * (1.f / 1024.f) - mu * mu;
  float rs = rsqrtf(var + 1e-6f);
  int c = tid * 4;
  us4 o4;
  o4.x = f2bf((v.x - mu) * rs * sc[c + 0] + bi[c + 0]);
  o4.y = f2bf((v.y - mu) * rs * sc[c + 1] + bi[c + 1]);
  o4.z = f2bf((v.z - mu) * rs * sc[c + 2] + bi[c + 2]);
  o4.w = f2bf((v.w - mu) * rs * sc[c + 3] + bi[c + 3]);
  *(us4*)(y + (size_t)row * 1024 + c) = o4;
}

// ---------------------------------------------------------------------------
// bf16 GEMM, C = A[M][K] * Bt[N][K]. 128x128 tile, BK=32, 16x16x32 MFMA.
// global_load_lds staging (width 16), double-buffered LDS, 1 barrier/K-step.
// Chunked XCD swizzle: XCD x owns tiles [x*cpx,(x+1)*cpx), bx fastest.
// EPI 1: bias+gelu -> bf16. EPI 2: res (+bias) -> fp32.
// EPI 3: fp32 + bf16 dual store. EPI 4: bf16 store.
// ---------------------------------------------------------------------------
#define GBM 128
#define GBN 128
#define GBK 32

template <int EPI>
__global__ __launch_bounds__(256) void gemm_bt(
    const unsigned short* __restrict__ A, const unsigned short* __restrict__ Bt,
    const float* __restrict__ bias, const float* __restrict__ res,
    float* __restrict__ Cf, unsigned short* __restrict__ Cb, int M, int N,
    int K) {
  __shared__ unsigned short sA[2][GBM * GBK];
  __shared__ unsigned short sB[2][GBN * GBK];
  const int nbx = N / GBN;
  // chunked XCD swizzle (grid is always a multiple of 8)
  const int nwg = gridDim.x;
  const int cpx = nwg >> 3;
  const int bid = blockIdx.x;
  const int swz = (bid & 7) * cpx + (bid >> 3);
  const int bx = swz % nbx;
  const int by = swz / nbx;
  const int tid = threadIdx.x;
  const int lane = tid & 63;
  const int wave = tid >> 6;
  const int wr = wave >> 1, wc = wave & 1;
  const unsigned short* Abase = A + (size_t)(by * GBM) * K;
  const unsigned short* Bbase = Bt + (size_t)(bx * GBN) * K;

  // staging: wave w covers rows [w*32, w*32+32). Lane l -> row w*32+(l>>2)
  // (+16 for the second load), col (l&3)*8. LDS linear [row][32]:
  // byte offset (l>>2)*64+(l&3)*16 == 16*l  => matches HW base+lane*16.
  const int strow = wave * 32 + (lane >> 2);
  const int stcol = (lane & 3) * 8;
  const unsigned short* Ag = Abase + (size_t)strow * K + stcol;
  const unsigned short* Bg = Bbase + (size_t)strow * K + stcol;
  const int ldsoff = wave * 32 * GBK;       // elements
  const int ldsoff2 = ldsoff + 16 * GBK;    // rows +16

  f32x4 acc[4][4];
#pragma unroll
  for (int m = 0; m < 4; ++m)
#pragma unroll
    for (int n = 0; n < 4; ++n) {
      f32x4 z = {0.f, 0.f, 0.f, 0.f};
      acc[m][n] = z;
    }

  const int KT = K / GBK;
  load_lds16(Ag, &sA[0][ldsoff]);
  load_lds16(Ag + (size_t)16 * K, &sA[0][ldsoff2]);
  load_lds16(Bg, &sB[0][ldsoff]);
  load_lds16(Bg + (size_t)16 * K, &sB[0][ldsoff2]);
  __syncthreads();

  int cur = 0;
  const int arow = wr * 64 + (lane & 15);
  const int brow = wc * 64 + (lane & 15);
  const int koff = (lane >> 4) * 8;

  for (int kt = 0; kt < KT; ++kt) {
    if (kt + 1 < KT) {
      const unsigned short* An = Ag + (size_t)(kt + 1) * GBK;
      const unsigned short* Bn = Bg + (size_t)(kt + 1) * GBK;
      load_lds16(An, &sA[cur ^ 1][ldsoff]);
      load_lds16(An + (size_t)16 * K, &sA[cur ^ 1][ldsoff2]);
      load_lds16(Bn, &sB[cur ^ 1][ldsoff]);
      load_lds16(Bn + (size_t)16 * K, &sB[cur ^ 1][ldsoff2]);
    }
    short8 af[4], bfv[4];
#pragma unroll
    for (int m = 0; m < 4; ++m)
      af[m] = *(const short8*)&sA[cur][(arow + m * 16) * GBK + koff];
#pragma unroll
    for (int n = 0; n < 4; ++n)
      bfv[n] = *(const short8*)&sB[cur][(brow + n * 16) * GBK + koff];
#pragma unroll
    for (int m = 0; m < 4; ++m)
#pragma unroll
      for (int n = 0; n < 4; ++n)
        acc[m][n] = __builtin_amdgcn_mfma_f32_16x16x32_bf16(af[m], bfv[n],
                                                            acc[m][n], 0, 0, 0);
    __syncthreads();
    cur ^= 1;
  }

  const int r0 = by * GBM + wr * 64;
  const int c0 = bx * GBN + wc * 64;
#pragma unroll
  for (int m = 0; m < 4; ++m) {
#pragma unroll
    for (int n = 0; n < 4; ++n) {
#pragma unroll
      for (int i = 0; i < 4; ++i) {
        int rr = r0 + m * 16 + ((lane >> 4) << 2) + i;
        int cc = c0 + n * 16 + (lane & 15);
        float vacc = acc[m][n][i];
        if (EPI == 1) {
          float t = vacc + bias[cc];
          Cb[(size_t)rr * N + cc] = f2bf(gelu_f(t));
        } else if (EPI == 2) {
          float t = vacc + res[(size_t)rr * N + cc];
          if (bias != nullptr) t += bias[cc];
          Cf[(size_t)rr * N + cc] = t;
        } else if (EPI == 3) {
          Cf[(size_t)rr * N + cc] = vacc;
          Cb[(size_t)rr * N + cc] = f2bf(vacc);
        } else if (EPI == 4) {
          Cb[(size_t)rr * N + cc] = f2bf(vacc);
        }
      }
    }
  }
}

// ---------------------------------------------------------------------------
// Buckets + normalized-K pack. One wave per (b,h,s) token.
// Writes knb = bf16(qk/(|qk|+1e-6)) and buckets.
// ---------------------------------------------------------------------------
__global__ __launch_bounds__(256) void bucket_kernel(
    const float* __restrict__ qk, const float* __restrict__ rot,
    unsigned short* __restrict__ knb, int* __restrict__ buckets) {
  __shared__ float rotl[64 * 64];
  __shared__ float xnl[4][64];
  int tid = threadIdx.x, lane = tid & 63, wv = tid >> 6;
  for (int i = tid; i < 4096; i += 256) rotl[i] = rot[i];
  __syncthreads();
  for (int it = 0; it < 8; ++it) {
    int g = (it * 4096 + blockIdx.x) * 4 + wv;
    int bh = g >> 12;
    int s = g & 4095;
    int b = bh >> 4, h = bh & 15;
    size_t rowoff = (size_t)(b * 4096 + s) * 1024 + h * 64;
    float x = qk[rowoff + lane];
    float ss = x * x;
#pragma unroll
    for (int o = 1; o < 64; o <<= 1) ss += __shfl_xor(ss, o);
    float rn = 1.f / (sqrtf(ss) + 1e-6f);
    float xn = x * rn;
    knb[rowoff + lane] = f2bf(xn);
    xnl[wv][lane] = xn;
    __syncthreads();
    int r_ = lane >> 5, m_ = lane & 31;
    float a = 0.f;
#pragma unroll 16
    for (int d = 0; d < 64; ++d) a += xnl[wv][d] * rotl[d * 64 + r_ * 32 + m_];
    float bv;
    int bi;
    if (a >= 0.f) {
      bv = a;
      bi = m_;
    } else {
      bv = -a;
      bi = m_ + 32;
    }
#pragma unroll
    for (int o = 16; o >= 1; o >>= 1) {
      float ov = __shfl_xor(bv, o);
      int oi = __shfl_xor(bi, o);
      if (ov > bv || (ov == bv && oi < bi)) {
        bv = ov;
        bi = oi;
      }
    }
    if (m_ == 0) buckets[((size_t)bh * 2 + r_) * 4096 + s] = bi;
    __syncthreads();
  }
}

// ---------------------------------------------------------------------------
// Parallel stable counting sort. One block (256 threads) per (b,h,r).
// ---------------------------------------------------------------------------
#define HSTR 65

__global__ __launch_bounds__(256) void sort_kernel(
    const int* __restrict__ buckets, int* __restrict__ order) {
  __shared__ unsigned int hist[256 * HSTR];
  __shared__ unsigned int bucketStart[64];
  const int bhr = blockIdx.x;
  const int t = threadIdx.x;
  const int* bk = buckets + (size_t)bhr * 4096;

  unsigned int* hrow = &hist[t * HSTR];
#pragma unroll
  for (int b = 0; b < 64; ++b) hrow[b] = 0u;

  int bks[16];
  {
    const int4* bp = (const int4*)(bk + t * 16);
#pragma unroll
    for (int j4 = 0; j4 < 4; ++j4) {
      int4 v = bp[j4];
      bks[j4 * 4 + 0] = v.x;
      bks[j4 * 4 + 1] = v.y;
      bks[j4 * 4 + 2] = v.z;
      bks[j4 * 4 + 3] = v.w;
    }
  }
#pragma unroll
  for (int j = 0; j < 16; ++j) hrow[bks[j]]++;
  __syncthreads();

  if (t < 64) {
    unsigned int acc = 0;
    for (int t2 = 0; t2 < 256; ++t2) {
      unsigned int c = hist[t2 * HSTR + t];
      hist[t2 * HSTR + t] = acc;
      acc += c;
    }
    bucketStart[t] = acc;
  }
  __syncthreads();
  if (t == 0) {
    unsigned int acc = 0;
    for (int b = 0; b < 64; ++b) {
      unsigned int c = bucketStart[b];
      bucketStart[b] = acc;
      acc += c;
    }
  }
  __syncthreads();

  int* op = order + (size_t)bhr * 4096;
#pragma unroll
  for (int j = 0; j < 16; ++j) {
    int b = bks[j];
    unsigned int pos = bucketStart[b] + hrow[b];
    hrow[b]++;
    op[pos] = t * 16 + j;
  }
}

// ---------------------------------------------------------------------------
// MFMA LSH attention, all-bf16 data path. One block per (b,h,r,chunk);
// chunked XCD swizzle so all 32 chunks of one (b,h,r) share an XCD's L2.
// ---------------------------------------------------------------------------
#define KSTR 72
#define PSTR 136

__global__ __launch_bounds__(256, 2) void lsh_attn_mfma(
    const unsigned short* __restrict__ qb, const unsigned short* __restrict__ knb,
    const unsigned short* __restrict__ vb, const int* __restrict__ order,
    unsigned short* __restrict__ ob, float* __restrict__ slog) {
  __shared__ unsigned short Kls[128 * KSTR];
  __shared__ unsigned short Vt[64 * PSTR];
  __shared__ unsigned short Pls[4][32 * PSTR];
  __shared__ int qtokL[128];
  __shared__ int btok[128];

  const int bid = blockIdx.x;                   // grid = 2048
  const int swz = (bid & 7) * 256 + (bid >> 3); // chunked XCD swizzle
  const int c = swz & 31;
  const int bhr = swz >> 5;
  const int bh = bhr >> 1;
  const int h = bh & 15, b = bh >> 4;
  const int* ord = order + (size_t)bhr * 4096;
  const int tid = threadIdx.x, lane = tid & 63, wv = tid >> 6;
  const int l15 = lane & 15, lhi = lane >> 4;

  if (tid < 128) qtokL[tid] = ord[c * 128 + tid];
  __syncthreads();

  short8 qf[2][2];
#pragma unroll
  for (int mt = 0; mt < 2; ++mt) {
#pragma unroll
    for (int ks = 0; ks < 2; ++ks) {
      int tok = qtokL[wv * 32 + mt * 16 + l15];
      qf[mt][ks] = *(const short8*)(qb + (size_t)(b * 4096 + tok) * 1024 +
                                    h * 64 + ks * 32 + lhi * 8);
    }
  }

  float mrun[2][4], lrun[2][4];
  f32x4 oacc[2][4];
#pragma unroll
  for (int mt = 0; mt < 2; ++mt)
#pragma unroll
    for (int i = 0; i < 4; ++i) {
      mrun[mt][i] = -1e30f;
      lrun[mt][i] = 0.f;
    }
#pragma unroll
  for (int mt = 0; mt < 2; ++mt)
#pragma unroll
    for (int n = 0; n < 4; ++n) {
      f32x4 z = {0.f, 0.f, 0.f, 0.f};
      oacc[mt][n] = z;
    }

  for (int st = 0; st < 3; ++st) {
    int kc = (st == 0) ? c : (st == 1) ? ((c + 31) & 31) : ((c + 1) & 31);
    __syncthreads();
    {
      int row = tid >> 1, half = tid & 1;
      int ktok = ord[kc * 128 + row];
      if (half == 0) btok[row] = ktok;
      size_t rowoff = (size_t)(b * 4096 + ktok) * 1024 + h * 64 + half * 32;
      const short8* kp = (const short8*)(knb + rowoff);
      const short8* vp = (const short8*)(vb + rowoff);
#pragma unroll
      for (int i = 0; i < 4; ++i)
        *(short8*)&Kls[row * KSTR + half * 32 + i * 8] = kp[i];
#pragma unroll
      for (int i = 0; i < 4; ++i) {
        short8 vw = vp[i];
        int d0 = half * 32 + i * 8;
#pragma unroll
        for (int j = 0; j < 8; ++j)
          Vt[(d0 + j) * PSTR + row] = (unsigned short)vw[j];
      }
    }
    __syncthreads();

    f32x4 sacc[2][8];
#pragma unroll
    for (int mt = 0; mt < 2; ++mt)
#pragma unroll
      for (int n = 0; n < 8; ++n) {
        f32x4 z = {0.f, 0.f, 0.f, 0.f};
        sacc[mt][n] = z;
      }
#pragma unroll
    for (int ks = 0; ks < 2; ++ks) {
      short8 kf[8];
#pragma unroll
      for (int n = 0; n < 8; ++n)
        kf[n] = *(const short8*)&Kls[(n * 16 + l15) * KSTR + ks * 32 + lhi * 8];
#pragma unroll
      for (int mt = 0; mt < 2; ++mt)
#pragma unroll
        for (int n = 0; n < 8; ++n)
          sacc[mt][n] = __builtin_amdgcn_mfma_f32_16x16x32_bf16(
              qf[mt][ks], kf[n], sacc[mt][n], 0, 0, 0);
    }

    int ktA[8];
#pragma unroll
    for (int n = 0; n < 8; ++n) ktA[n] = btok[n * 16 + l15];
#pragma unroll
    for (int mt = 0; mt < 2; ++mt) {
#pragma unroll
      for (int i = 0; i < 4; ++i) {
        int qrow = wv * 32 + mt * 16 + lhi * 4 + i;
        int qt = qtokL[qrow];
        float sv[8];
        float mx = -1e30f;
#pragma unroll
        for (int n = 0; n < 8; ++n) {
          float s = sacc[mt][n][i] * 0.125f;
          if (ktA[n] == qt) s -= 1e5f;
          sv[n] = s;
          mx = fmaxf(mx, s);
        }
#pragma unroll
        for (int d = 1; d < 16; d <<= 1) mx = fmaxf(mx, __shfl_xor(mx, d));
        float mold = mrun[mt][i];
        float mnew = fmaxf(mold, mx);
        float scl = __expf(mold - mnew);
        lrun[mt][i] *= scl;
#pragma unroll
        for (int n = 0; n < 4; ++n) oacc[mt][n][i] *= scl;
        float ps = 0.f;
#pragma unroll
        for (int n = 0; n < 8; ++n) {
          float p = __expf(sv[n] - mnew);
          ps += p;
          Pls[wv][(mt * 16 + lhi * 4 + i) * PSTR + n * 16 + l15] = f2bf(p);
        }
#pragma unroll
        for (int d = 1; d < 16; d <<= 1) ps += __shfl_xor(ps, d);
        lrun[mt][i] = lrun[mt][i] + ps;
        mrun[mt][i] = mnew;
      }
    }

#pragma unroll
    for (int ks = 0; ks < 4; ++ks) {
      short8 pf[2];
#pragma unroll
      for (int mt = 0; mt < 2; ++mt)
        pf[mt] =
            *(const short8*)&Pls[wv][(mt * 16 + l15) * PSTR + ks * 32 + lhi * 8];
      short8 vfr[4];
#pragma unroll
      for (int n = 0; n < 4; ++n)
        vfr[n] = *(const short8*)&Vt[(n * 16 + l15) * PSTR + ks * 32 + lhi * 8];
#pragma unroll
      for (int mt = 0; mt < 2; ++mt)
#pragma unroll
        for (int n = 0; n < 4; ++n)
          oacc[mt][n] = __builtin_amdgcn_mfma_f32_16x16x32_bf16(
              pf[mt], vfr[n], oacc[mt][n], 0, 0, 0);
    }
  }

#pragma unroll
  for (int mt = 0; mt < 2; ++mt) {
#pragma unroll
    for (int i = 0; i < 4; ++i) {
      int qrow = wv * 32 + mt * 16 + lhi * 4 + i;
      int tok = qtokL[qrow];
      float l = lrun[mt][i];
      float invl = 1.f / l;
      if (l15 == 0) slog[(size_t)bhr * 4096 + tok] = logf(l) + mrun[mt][i];
      unsigned short* orow = ob + ((size_t)bhr * 4096 + tok) * 64;
#pragma unroll
      for (int n = 0; n < 4; ++n)
        orow[n * 16 + l15] = f2bf(oacc[mt][n][i] * invl);
    }
  }
}

// ---------------------------------------------------------------------------
// Combine hash rounds: w = softmax over r of slog; att = sum_r w_r * o_r.
// ---------------------------------------------------------------------------
__global__ __launch_bounds__(256) void combine_rounds(
    const unsigned short* __restrict__ ob, const float* __restrict__ slog,
    unsigned short* __restrict__ att) {
  int g = blockIdx.x * 4 + (threadIdx.x >> 6);
  int lane = threadIdx.x & 63;
  int h = g & 15;
  int bs = g >> 4;
  int b = bs >> 12;
  int s = bs & 4095;
  size_t base = ((size_t)(b * 16 + h) * 2) * 4096 + s;
  size_t i0 = base;
  size_t i1 = base + 4096;
  float s0 = slog[i0], s1 = slog[i1];
  float mx = fmaxf(s0, s1);
  float e0 = __expf(s0 - mx), e1 = __expf(s1 - mx);
  float w0 = e0 / (e0 + e1);
  float w1 = 1.f - w0;
  float v0 = bf2f(ob[i0 * 64 + lane]);
  float v1 = bf2f(ob[i1 * 64 + lane]);
  att[(size_t)bs * 1024 + h * 64 + lane] = f2bf(w0 * v0 + w1 * v1);
}

// ---------------------------------------------------------------------------
extern "C" void kernel_launch(void* const* d_in, const int* in_sizes, int n_in,
                              void* d_out, int out_size, void* d_ws,
                              size_t ws_size, hipStream_t stream) {
  const float* inputs = (const float*)d_in[0];
  const float* ln1s = (const float*)d_in[1];
  const float* ln1b = (const float*)d_in[2];
  const float* wqk = (const float*)d_in[3];
  const float* wv = (const float*)d_in[4];
  const float* wout = (const float*)d_in[5];
  const float* rot = (const float*)d_in[6];
  const float* ln2s = (const float*)d_in[7];
  const float* ln2b = (const float*)d_in[8];
  const float* wm1 = (const float*)d_in[9];
  const float* bm1 = (const float*)d_in[10];
  const float* wm2 = (const float*)d_in[11];
  const float* bm2 = (const float*)d_in[12];

  char* w = (char*)d_ws;
  auto alloc = [&](size_t bytes) {
    char* p = w;
    w += (bytes + 255) & ~(size_t)255;
    return p;
  };
  unsigned short* wqk_bt = (unsigned short*)alloc(1024ull * 1024 * 2);
  unsigned short* wv_bt = (unsigned short*)alloc(1024ull * 1024 * 2);
  unsigned short* wout_bt = (unsigned short*)alloc(1024ull * 1024 * 2);
  unsigned short* wm1_bt = (unsigned short*)alloc(4096ull * 1024 * 2);
  unsigned short* wm2_bt = (unsigned short*)alloc(1024ull * 4096 * 2);
  unsigned short* bufA = (unsigned short*)alloc(8192ull * 1024 * 2);
  float* qkf = (float*)alloc(8192ull * 1024 * 4);  // dead after buckets -> x2
  unsigned short* qb = (unsigned short*)alloc(8192ull * 1024 * 2);
  unsigned short* knb = (unsigned short*)alloc(8192ull * 1024 * 2);
  unsigned short* vb = (unsigned short*)alloc(8192ull * 1024 * 2);
  int* buckets = (int*)alloc(64ull * 4096 * 4);
  int* order = (int*)alloc(64ull * 4096 * 4);
  unsigned short* big =
      (unsigned short*)alloc(8192ull * 4096 * 2);  // obuf then h1
  float* slogb = (float*)alloc(64ull * 4096 * 4);
  float* x2 = qkf;
  unsigned short* obuf = big;
  unsigned short* h1 = big;

  transpose_cast<<<32 * 32, 256, 0, stream>>>(wqk, wqk_bt, 1024, 1024);
  transpose_cast<<<32 * 32, 256, 0, stream>>>(wv, wv_bt, 1024, 1024);
  transpose_cast<<<32 * 32, 256, 0, stream>>>(wout, wout_bt, 1024, 1024);
  transpose_cast<<<32 * 128, 256, 0, stream>>>(wm1, wm1_bt, 1024, 4096);
  transpose_cast<<<128 * 32, 256, 0, stream>>>(wm2, wm2_bt, 4096, 1024);

  ln_bf16<<<8192, 256, 0, stream>>>(inputs, ln1s, ln1b, bufA);

  // qk: fp32 (for buckets) + bf16 (for attention); v: bf16 only
  gemm_bt<3><<<64 * 8, 256, 0, stream>>>(bufA, wqk_bt, nullptr, nullptr, qkf,
                                         qb, 8192, 1024, 1024);
  gemm_bt<4><<<64 * 8, 256, 0, stream>>>(bufA, wv_bt, nullptr, nullptr, nullptr,
                                         vb, 8192, 1024, 1024);

  bucket_kernel<<<4096, 256, 0, stream>>>(qkf, rot, knb, buckets);
  sort_kernel<<<64, 256, 0, stream>>>(buckets, order);
  lsh_attn_mfma<<<2048, 256, 0, stream>>>(qb, knb, vb, order, obuf, slogb);
  combine_rounds<<<32768, 256, 0, stream>>>(obuf, slogb, bufA);

  gemm_bt<2><<<64 * 8, 256, 0, stream>>>(bufA, wout_bt, nullptr, inputs, x2,
                                         nullptr, 8192, 1024, 1024);
  ln_bf16<<<8192, 256, 0, stream>>>(x2, ln2s, ln2b, bufA);
  gemm_bt<1><<<64 * 32, 256, 0, stream>>>(bufA, wm1_bt, bm1, nullptr, nullptr,
                                          h1, 8192, 4096, 1024);
  gemm_bt<2><<<64 * 8, 256, 0, stream>>>(h1, wm2_bt, bm2, x2, (float*)d_out,
                                         nullptr, 8192, 1024, 4096);
}

// Round 7
// 517.283 us; speedup vs baseline: 2.6761x; 1.0388x over previous
//
#include <hip/hip_runtime.h>
#include <hip/hip_bf16.h>

// ---------------------------------------------------------------------------
// ReformerBlockPreLN on MI355X — round 6: GEMM ring-4 counted-vmcnt schedule
// (T3/T4) + LDS granule XOR swizzle (T2) + setprio (T5). Rest unchanged.
// B=2 S=4096 D=1024 H=16 DH=64 R=2 NBUCK=64 CHUNK=128 MLP=4096
// ---------------------------------------------------------------------------

typedef short short8 __attribute__((ext_vector_type(8)));
typedef float f32x4 __attribute__((ext_vector_type(4)));
typedef unsigned short us4 __attribute__((ext_vector_type(4)));

__device__ __forceinline__ unsigned short f2bf(float f) {
  unsigned u = __builtin_bit_cast(unsigned, f);
  u += 0x7FFFu + ((u >> 16) & 1u);
  return (unsigned short)(u >> 16);
}

__device__ __forceinline__ float bf2f(unsigned short u) {
  return __builtin_bit_cast(float, ((unsigned)u) << 16);
}

__device__ __forceinline__ float gelu_f(float x) {
  float x3 = x * x * x;
  float t = tanhf(0.7978845608028654f * (x + 0.044715f * x3));
  return 0.5f * x * (1.0f + t);
}

__device__ __forceinline__ void load_lds16(const void* g, void* l) {
  __builtin_amdgcn_global_load_lds(
      (const __attribute__((address_space(1))) unsigned int*)g,
      (__attribute__((address_space(3))) unsigned int*)l, 16, 0, 0);
}

// ---------------------------------------------------------------------------
// transpose + cast fp32 [R][C] -> bf16 [C][R]
// ---------------------------------------------------------------------------
__global__ __launch_bounds__(256) void transpose_cast(
    const float* __restrict__ in, unsigned short* __restrict__ out, int R,
    int C) {
  __shared__ float tile[32][33];
  int ctiles = C >> 5;
  int bx = blockIdx.x % ctiles;
  int by = blockIdx.x / ctiles;
  int tx = threadIdx.x & 31;
  int ty = threadIdx.x >> 5;
#pragma unroll
  for (int i = 0; i < 32; i += 8)
    tile[ty + i][tx] = in[(size_t)(by * 32 + ty + i) * C + bx * 32 + tx];
  __syncthreads();
#pragma unroll
  for (int i = 0; i < 32; i += 8)
    out[(size_t)(bx * 32 + ty + i) * R + by * 32 + tx] = f2bf(tile[tx][ty + i]);
}

// ---------------------------------------------------------------------------
// LayerNorm over D=1024, fp32 in -> bf16 out. One block per row.
// ---------------------------------------------------------------------------
__global__ __launch_bounds__(256) void ln_bf16(const float* __restrict__ x,
                                               const float* __restrict__ sc,
                                               const float* __restrict__ bi,
                                               unsigned short* __restrict__ y) {
  int row = blockIdx.x, tid = threadIdx.x, lane = tid & 63, wv = tid >> 6;
  const float* xr = x + (size_t)row * 1024;
  float4 v = *(const float4*)(xr + tid * 4);
  float s1 = v.x + v.y + v.z + v.w;
  float s2 = v.x * v.x + v.y * v.y + v.z * v.z + v.w * v.w;
#pragma unroll
  for (int o = 1; o < 64; o <<= 1) {
    s1 += __shfl_xor(s1, o);
    s2 += __shfl_xor(s2, o);
  }
  __shared__ float a1[4], a2[4];
  if (lane == 0) {
    a1[wv] = s1;
    a2[wv] = s2;
  }
  __syncthreads();
  s1 = a1[0] + a1[1] + a1[2] + a1[3];
  s2 = a2[0] + a2[1] + a2[2] + a2[3];
  float mu = s1 * (1.f / 1024.f);
  float var = s2 * (1.f / 1024.f) - mu * mu;
  float rs = rsqrtf(var + 1e-6f);
  int c = tid * 4;
  us4 o4;
  o4.x = f2bf((v.x - mu) * rs * sc[c + 0] + bi[c + 0]);
  o4.y = f2bf((v.y - mu) * rs * sc[c + 1] + bi[c + 1]);
  o4.z = f2bf((v.z - mu) * rs * sc[c + 2] + bi[c + 2]);
  o4.w = f2bf((v.w - mu) * rs * sc[c + 3] + bi[c + 3]);
  *(us4*)(y + (size_t)row * 1024 + c) = o4;
}

// ---------------------------------------------------------------------------
// bf16 GEMM, C = A[M][K] * Bt[N][K]. 128x128 tile, BK=32, 16x16x32 MFMA.
// 4-deep LDS ring, counted vmcnt (never drains in main loop), raw s_barrier,
// granule XOR swizzle (pre-swizzled global source, swizzled ds_read),
// setprio around MFMA cluster. Chunked XCD swizzle on blockIdx.
// EPI 1: bias+gelu -> bf16. EPI 2: res (+bias) -> fp32.
// EPI 3: fp32 + bf16 dual store. EPI 4: bf16 store.
// ---------------------------------------------------------------------------
#define GBM 128
#define GBN 128
#define GBK 32

template <int EPI>
__global__ __launch_bounds__(256) void gemm_bt(
    const unsigned short* __restrict__ A, const unsigned short* __restrict__ Bt,
    const float* __restrict__ bias, const float* __restrict__ res,
    float* __restrict__ Cf, unsigned short* __restrict__ Cb, int M, int N,
    int K) {
  __shared__ unsigned short sA[4][GBM * GBK];
  __shared__ unsigned short sB[4][GBN * GBK];
  const int nbx = N / GBN;
  const int nwg = gridDim.x;
  const int cpx = nwg >> 3;
  const int bid = blockIdx.x;
  const int swz = (bid & 7) * cpx + (bid >> 3);
  const int bx = swz % nbx;
  const int by = swz / nbx;
  const int tid = threadIdx.x;
  const int lane = tid & 63;
  const int wave = tid >> 6;
  const int wr = wave >> 1, wc = wave & 1;
  const unsigned short* Abase = A + (size_t)(by * GBM) * K;
  const unsigned short* Bbase = Bt + (size_t)(bx * GBN) * K;

  // --- staging geometry (wave-linear LDS dest = base + lane*16) ---
  // lane -> local row wave*32 + (lane>>2) (+16 for 2nd instr), phys granule
  // lane&3. Swizzle: phys (row,g) holds logical granule g ^ ((row>>1)&3),
  // so the global source column is pre-permuted by the same XOR.
  const int srow_l = wave * 32 + (lane >> 2);
  const int sgl = (lane & 3) ^ ((srow_l >> 1) & 3);  // same for rows +16
  const unsigned short* Ag = Abase + (size_t)srow_l * K + sgl * 8;
  const unsigned short* Bg = Bbase + (size_t)srow_l * K + sgl * 8;
  const int ldsoff = wave * 32 * GBK;
  const int ldsoff2 = ldsoff + 16 * GBK;

  f32x4 acc[4][4];
#pragma unroll
  for (int m = 0; m < 4; ++m)
#pragma unroll
    for (int n = 0; n < 4; ++n) {
      f32x4 z = {0.f, 0.f, 0.f, 0.f};
      acc[m][n] = z;
    }

  const int KT = K / GBK;

#define STAGE(ktile, slot)                                             \
  do {                                                                 \
    const unsigned short* An_ = Ag + (size_t)(ktile)*GBK;              \
    const unsigned short* Bn_ = Bg + (size_t)(ktile)*GBK;              \
    load_lds16(An_, &sA[(slot)][ldsoff]);                              \
    load_lds16(An_ + (size_t)16 * K, &sA[(slot)][ldsoff2]);            \
    load_lds16(Bn_, &sB[(slot)][ldsoff]);                              \
    load_lds16(Bn_ + (size_t)16 * K, &sB[(slot)][ldsoff2]);            \
  } while (0)

  // prologue: stage tiles 0,1,2 (12 loads); retire tile 0 (leave 8 in flight)
  STAGE(0, 0);
  STAGE(1, 1);
  STAGE(2, 2);
  asm volatile("s_waitcnt vmcnt(8)" ::: "memory");
  __builtin_amdgcn_sched_barrier(0);
  __builtin_amdgcn_s_barrier();

  const int l15 = lane & 15;
  const int lhi = lane >> 4;
  const int arowb = wr * 64 + l15;
  const int browb = wc * 64 + l15;
  // swizzled read granule: logical granule lhi at row (..+l15+16m) ->
  // phys lhi ^ ((l15>>1)&3)  (16m and 64*w do not affect (row>>1)&3)
  const int gsw = (lhi ^ ((l15 >> 1) & 3)) * 8;

  for (int kt = 0; kt < KT; ++kt) {
    const int slot = kt & 3;
    short8 af[4], bfv[4];
#pragma unroll
    for (int m = 0; m < 4; ++m)
      af[m] = *(const short8*)&sA[slot][(arowb + m * 16) * GBK + gsw];
#pragma unroll
    for (int n = 0; n < 4; ++n)
      bfv[n] = *(const short8*)&sB[slot][(browb + n * 16) * GBK + gsw];
    if (kt + 3 < KT) STAGE(kt + 3, (kt + 3) & 3);
    __builtin_amdgcn_s_setprio(1);
#pragma unroll
    for (int m = 0; m < 4; ++m)
#pragma unroll
      for (int n = 0; n < 4; ++n)
        acc[m][n] = __builtin_amdgcn_mfma_f32_16x16x32_bf16(af[m], bfv[n],
                                                            acc[m][n], 0, 0, 0);
    __builtin_amdgcn_s_setprio(0);
    // retire tile kt+1's loads before next iteration reads it (block-wide
    // via the barrier); never drain to 0 while stages remain in flight.
    if (kt + 3 < KT) {
      asm volatile("s_waitcnt vmcnt(8)" ::: "memory");
    } else if (kt + 2 < KT) {
      asm volatile("s_waitcnt vmcnt(4)" ::: "memory");
    } else if (kt + 1 < KT) {
      asm volatile("s_waitcnt vmcnt(0)" ::: "memory");
    }
    __builtin_amdgcn_sched_barrier(0);
    __builtin_amdgcn_s_barrier();
  }
#undef STAGE

  const int r0 = by * GBM + wr * 64;
  const int c0 = bx * GBN + wc * 64;
#pragma unroll
  for (int m = 0; m < 4; ++m) {
#pragma unroll
    for (int n = 0; n < 4; ++n) {
#pragma unroll
      for (int i = 0; i < 4; ++i) {
        int rr = r0 + m * 16 + ((lane >> 4) << 2) + i;
        int cc = c0 + n * 16 + (lane & 15);
        float vacc = acc[m][n][i];
        if (EPI == 1) {
          float t = vacc + bias[cc];
          Cb[(size_t)rr * N + cc] = f2bf(gelu_f(t));
        } else if (EPI == 2) {
          float t = vacc + res[(size_t)rr * N + cc];
          if (bias != nullptr) t += bias[cc];
          Cf[(size_t)rr * N + cc] = t;
        } else if (EPI == 3) {
          Cf[(size_t)rr * N + cc] = vacc;
          Cb[(size_t)rr * N + cc] = f2bf(vacc);
        } else if (EPI == 4) {
          Cb[(size_t)rr * N + cc] = f2bf(vacc);
        }
      }
    }
  }
}

// ---------------------------------------------------------------------------
// Buckets + normalized-K pack. One wave per (b,h,s) token.
// ---------------------------------------------------------------------------
__global__ __launch_bounds__(256) void bucket_kernel(
    const float* __restrict__ qk, const float* __restrict__ rot,
    unsigned short* __restrict__ knb, int* __restrict__ buckets) {
  __shared__ float rotl[64 * 64];
  __shared__ float xnl[4][64];
  int tid = threadIdx.x, lane = tid & 63, wv = tid >> 6;
  for (int i = tid; i < 4096; i += 256) rotl[i] = rot[i];
  __syncthreads();
  for (int it = 0; it < 8; ++it) {
    int g = (it * 4096 + blockIdx.x) * 4 + wv;
    int bh = g >> 12;
    int s = g & 4095;
    int b = bh >> 4, h = bh & 15;
    size_t rowoff = (size_t)(b * 4096 + s) * 1024 + h * 64;
    float x = qk[rowoff + lane];
    float ss = x * x;
#pragma unroll
    for (int o = 1; o < 64; o <<= 1) ss += __shfl_xor(ss, o);
    float rn = 1.f / (sqrtf(ss) + 1e-6f);
    float xn = x * rn;
    knb[rowoff + lane] = f2bf(xn);
    xnl[wv][lane] = xn;
    __syncthreads();
    int r_ = lane >> 5, m_ = lane & 31;
    float a = 0.f;
#pragma unroll 16
    for (int d = 0; d < 64; ++d) a += xnl[wv][d] * rotl[d * 64 + r_ * 32 + m_];
    float bv;
    int bi;
    if (a >= 0.f) {
      bv = a;
      bi = m_;
    } else {
      bv = -a;
      bi = m_ + 32;
    }
#pragma unroll
    for (int o = 16; o >= 1; o >>= 1) {
      float ov = __shfl_xor(bv, o);
      int oi = __shfl_xor(bi, o);
      if (ov > bv || (ov == bv && oi < bi)) {
        bv = ov;
        bi = oi;
      }
    }
    if (m_ == 0) buckets[((size_t)bh * 2 + r_) * 4096 + s] = bi;
    __syncthreads();
  }
}

// ---------------------------------------------------------------------------
// Parallel stable counting sort. One block (256 threads) per (b,h,r).
// ---------------------------------------------------------------------------
#define HSTR 65

__global__ __launch_bounds__(256) void sort_kernel(
    const int* __restrict__ buckets, int* __restrict__ order) {
  __shared__ unsigned int hist[256 * HSTR];
  __shared__ unsigned int bucketStart[64];
  const int bhr = blockIdx.x;
  const int t = threadIdx.x;
  const int* bk = buckets + (size_t)bhr * 4096;

  unsigned int* hrow = &hist[t * HSTR];
#pragma unroll
  for (int b = 0; b < 64; ++b) hrow[b] = 0u;

  int bks[16];
  {
    const int4* bp = (const int4*)(bk + t * 16);
#pragma unroll
    for (int j4 = 0; j4 < 4; ++j4) {
      int4 v = bp[j4];
      bks[j4 * 4 + 0] = v.x;
      bks[j4 * 4 + 1] = v.y;
      bks[j4 * 4 + 2] = v.z;
      bks[j4 * 4 + 3] = v.w;
    }
  }
#pragma unroll
  for (int j = 0; j < 16; ++j) hrow[bks[j]]++;
  __syncthreads();

  if (t < 64) {
    unsigned int acc = 0;
    for (int t2 = 0; t2 < 256; ++t2) {
      unsigned int c = hist[t2 * HSTR + t];
      hist[t2 * HSTR + t] = acc;
      acc += c;
    }
    bucketStart[t] = acc;
  }
  __syncthreads();
  if (t == 0) {
    unsigned int acc = 0;
    for (int b = 0; b < 64; ++b) {
      unsigned int c = bucketStart[b];
      bucketStart[b] = acc;
      acc += c;
    }
  }
  __syncthreads();

  int* op = order + (size_t)bhr * 4096;
#pragma unroll
  for (int j = 0; j < 16; ++j) {
    int b = bks[j];
    unsigned int pos = bucketStart[b] + hrow[b];
    hrow[b]++;
    op[pos] = t * 16 + j;
  }
}

// ---------------------------------------------------------------------------
// MFMA LSH attention, all-bf16 data path. One block per (b,h,r,chunk);
// chunked XCD swizzle so all 32 chunks of one (b,h,r) share an XCD's L2.
// ---------------------------------------------------------------------------
#define KSTR 72
#define PSTR 136

__global__ __launch_bounds__(256, 2) void lsh_attn_mfma(
    const unsigned short* __restrict__ qb, const unsigned short* __restrict__ knb,
    const unsigned short* __restrict__ vb, const int* __restrict__ order,
    unsigned short* __restrict__ ob, float* __restrict__ slog) {
  __shared__ unsigned short Kls[128 * KSTR];
  __shared__ unsigned short Vt[64 * PSTR];
  __shared__ unsigned short Pls[4][32 * PSTR];
  __shared__ int qtokL[128];
  __shared__ int btok[128];

  const int bid = blockIdx.x;                   // grid = 2048
  const int swz = (bid & 7) * 256 + (bid >> 3); // chunked XCD swizzle
  const int c = swz & 31;
  const int bhr = swz >> 5;
  const int bh = bhr >> 1;
  const int h = bh & 15, b = bh >> 4;
  const int* ord = order + (size_t)bhr * 4096;
  const int tid = threadIdx.x, lane = tid & 63, wv = tid >> 6;
  const int l15 = lane & 15, lhi = lane >> 4;

  if (tid < 128) qtokL[tid] = ord[c * 128 + tid];
  __syncthreads();

  short8 qf[2][2];
#pragma unroll
  for (int mt = 0; mt < 2; ++mt) {
#pragma unroll
    for (int ks = 0; ks < 2; ++ks) {
      int tok = qtokL[wv * 32 + mt * 16 + l15];
      qf[mt][ks] = *(const short8*)(qb + (size_t)(b * 4096 + tok) * 1024 +
                                    h * 64 + ks * 32 + lhi * 8);
    }
  }

  float mrun[2][4], lrun[2][4];
  f32x4 oacc[2][4];
#pragma unroll
  for (int mt = 0; mt < 2; ++mt)
#pragma unroll
    for (int i = 0; i < 4; ++i) {
      mrun[mt][i] = -1e30f;
      lrun[mt][i] = 0.f;
    }
#pragma unroll
  for (int mt = 0; mt < 2; ++mt)
#pragma unroll
    for (int n = 0; n < 4; ++n) {
      f32x4 z = {0.f, 0.f, 0.f, 0.f};
      oacc[mt][n] = z;
    }

  for (int st = 0; st < 3; ++st) {
    int kc = (st == 0) ? c : (st == 1) ? ((c + 31) & 31) : ((c + 1) & 31);
    __syncthreads();
    {
      int row = tid >> 1, half = tid & 1;
      int ktok = ord[kc * 128 + row];
      if (half == 0) btok[row] = ktok;
      size_t rowoff = (size_t)(b * 4096 + ktok) * 1024 + h * 64 + half * 32;
      const short8* kp = (const short8*)(knb + rowoff);
      const short8* vp = (const short8*)(vb + rowoff);
#pragma unroll
      for (int i = 0; i < 4; ++i)
        *(short8*)&Kls[row * KSTR + half * 32 + i * 8] = kp[i];
#pragma unroll
      for (int i = 0; i < 4; ++i) {
        short8 vw = vp[i];
        int d0 = half * 32 + i * 8;
#pragma unroll
        for (int j = 0; j < 8; ++j)
          Vt[(d0 + j) * PSTR + row] = (unsigned short)vw[j];
      }
    }
    __syncthreads();

    f32x4 sacc[2][8];
#pragma unroll
    for (int mt = 0; mt < 2; ++mt)
#pragma unroll
      for (int n = 0; n < 8; ++n) {
        f32x4 z = {0.f, 0.f, 0.f, 0.f};
        sacc[mt][n] = z;
      }
#pragma unroll
    for (int ks = 0; ks < 2; ++ks) {
      short8 kf[8];
#pragma unroll
      for (int n = 0; n < 8; ++n)
        kf[n] = *(const short8*)&Kls[(n * 16 + l15) * KSTR + ks * 32 + lhi * 8];
#pragma unroll
      for (int mt = 0; mt < 2; ++mt)
#pragma unroll
        for (int n = 0; n < 8; ++n)
          sacc[mt][n] = __builtin_amdgcn_mfma_f32_16x16x32_bf16(
              qf[mt][ks], kf[n], sacc[mt][n], 0, 0, 0);
    }

    int ktA[8];
#pragma unroll
    for (int n = 0; n < 8; ++n) ktA[n] = btok[n * 16 + l15];
#pragma unroll
    for (int mt = 0; mt < 2; ++mt) {
#pragma unroll
      for (int i = 0; i < 4; ++i) {
        int qrow = wv * 32 + mt * 16 + lhi * 4 + i;
        int qt = qtokL[qrow];
        float sv[8];
        float mx = -1e30f;
#pragma unroll
        for (int n = 0; n < 8; ++n) {
          float s = sacc[mt][n][i] * 0.125f;
          if (ktA[n] == qt) s -= 1e5f;
          sv[n] = s;
          mx = fmaxf(mx, s);
        }
#pragma unroll
        for (int d = 1; d < 16; d <<= 1) mx = fmaxf(mx, __shfl_xor(mx, d));
        float mold = mrun[mt][i];
        float mnew = fmaxf(mold, mx);
        float scl = __expf(mold - mnew);
        lrun[mt][i] *= scl;
#pragma unroll
        for (int n = 0; n < 4; ++n) oacc[mt][n][i] *= scl;
        float ps = 0.f;
#pragma unroll
        for (int n = 0; n < 8; ++n) {
          float p = __expf(sv[n] - mnew);
          ps += p;
          Pls[wv][(mt * 16 + lhi * 4 + i) * PSTR + n * 16 + l15] = f2bf(p);
        }
#pragma unroll
        for (int d = 1; d < 16; d <<= 1) ps += __shfl_xor(ps, d);
        lrun[mt][i] = lrun[mt][i] + ps;
        mrun[mt][i] = mnew;
      }
    }

#pragma unroll
    for (int ks = 0; ks < 4; ++ks) {
      short8 pf[2];
#pragma unroll
      for (int mt = 0; mt < 2; ++mt)
        pf[mt] =
            *(const short8*)&Pls[wv][(mt * 16 + l15) * PSTR + ks * 32 + lhi * 8];
      short8 vfr[4];
#pragma unroll
      for (int n = 0; n < 4; ++n)
        vfr[n] = *(const short8*)&Vt[(n * 16 + l15) * PSTR + ks * 32 + lhi * 8];
#pragma unroll
      for (int mt = 0; mt < 2; ++mt)
#pragma unroll
        for (int n = 0; n < 4; ++n)
          oacc[mt][n] = __builtin_amdgcn_mfma_f32_16x16x32_bf16(
              pf[mt], vfr[n], oacc[mt][n], 0, 0, 0);
    }
  }

#pragma unroll
  for (int mt = 0; mt < 2; ++mt) {
#pragma unroll
    for (int i = 0; i < 4; ++i) {
      int qrow = wv * 32 + mt * 16 + lhi * 4 + i;
      int tok = qtokL[qrow];
      float l = lrun[mt][i];
      float invl = 1.f / l;
      if (l15 == 0) slog[(size_t)bhr * 4096 + tok] = logf(l) + mrun[mt][i];
      unsigned short* orow = ob + ((size_t)bhr * 4096 + tok) * 64;
#pragma unroll
      for (int n = 0; n < 4; ++n)
        orow[n * 16 + l15] = f2bf(oacc[mt][n][i] * invl);
    }
  }
}

// ---------------------------------------------------------------------------
// Combine hash rounds: w = softmax over r of slog; att = sum_r w_r * o_r.
// ---------------------------------------------------------------------------
__global__ __launch_bounds__(256) void combine_rounds(
    const unsigned short* __restrict__ ob, const float* __restrict__ slog,
    unsigned short* __restrict__ att) {
  int g = blockIdx.x * 4 + (threadIdx.x >> 6);
  int lane = threadIdx.x & 63;
  int h = g & 15;
  int bs = g >> 4;
  int b = bs >> 12;
  int s = bs & 4095;
  size_t base = ((size_t)(b * 16 + h) * 2) * 4096 + s;
  size_t i0 = base;
  size_t i1 = base + 4096;
  float s0 = slog[i0], s1 = slog[i1];
  float mx = fmaxf(s0, s1);
  float e0 = __expf(s0 - mx), e1 = __expf(s1 - mx);
  float w0 = e0 / (e0 + e1);
  float w1 = 1.f - w0;
  float v0 = bf2f(ob[i0 * 64 + lane]);
  float v1 = bf2f(ob[i1 * 64 + lane]);
  att[(size_t)bs * 1024 + h * 64 + lane] = f2bf(w0 * v0 + w1 * v1);
}

// ---------------------------------------------------------------------------
extern "C" void kernel_launch(void* const* d_in, const int* in_sizes, int n_in,
                              void* d_out, int out_size, void* d_ws,
                              size_t ws_size, hipStream_t stream) {
  const float* inputs = (const float*)d_in[0];
  const float* ln1s = (const float*)d_in[1];
  const float* ln1b = (const float*)d_in[2];
  const float* wqk = (const float*)d_in[3];
  const float* wv = (const float*)d_in[4];
  const float* wout = (const float*)d_in[5];
  const float* rot = (const float*)d_in[6];
  const float* ln2s = (const float*)d_in[7];
  const float* ln2b = (const float*)d_in[8];
  const float* wm1 = (const float*)d_in[9];
  const float* bm1 = (const float*)d_in[10];
  const float* wm2 = (const float*)d_in[11];
  const float* bm2 = (const float*)d_in[12];

  char* w = (char*)d_ws;
  auto alloc = [&](size_t bytes) {
    char* p = w;
    w += (bytes + 255) & ~(size_t)255;
    return p;
  };
  unsigned short* wqk_bt = (unsigned short*)alloc(1024ull * 1024 * 2);
  unsigned short* wv_bt = (unsigned short*)alloc(1024ull * 1024 * 2);
  unsigned short* wout_bt = (unsigned short*)alloc(1024ull * 1024 * 2);
  unsigned short* wm1_bt = (unsigned short*)alloc(4096ull * 1024 * 2);
  unsigned short* wm2_bt = (unsigned short*)alloc(1024ull * 4096 * 2);
  unsigned short* bufA = (unsigned short*)alloc(8192ull * 1024 * 2);
  float* qkf = (float*)alloc(8192ull * 1024 * 4);  // dead after buckets -> x2
  unsigned short* qb = (unsigned short*)alloc(8192ull * 1024 * 2);
  unsigned short* knb = (unsigned short*)alloc(8192ull * 1024 * 2);
  unsigned short* vb = (unsigned short*)alloc(8192ull * 1024 * 2);
  int* buckets = (int*)alloc(64ull * 4096 * 4);
  int* order = (int*)alloc(64ull * 4096 * 4);
  unsigned short* big =
      (unsigned short*)alloc(8192ull * 4096 * 2);  // obuf then h1
  float* slogb = (float*)alloc(64ull * 4096 * 4);
  float* x2 = qkf;
  unsigned short* obuf = big;
  unsigned short* h1 = big;

  transpose_cast<<<32 * 32, 256, 0, stream>>>(wqk, wqk_bt, 1024, 1024);
  transpose_cast<<<32 * 32, 256, 0, stream>>>(wv, wv_bt, 1024, 1024);
  transpose_cast<<<32 * 32, 256, 0, stream>>>(wout, wout_bt, 1024, 1024);
  transpose_cast<<<32 * 128, 256, 0, stream>>>(wm1, wm1_bt, 1024, 4096);
  transpose_cast<<<128 * 32, 256, 0, stream>>>(wm2, wm2_bt, 4096, 1024);

  ln_bf16<<<8192, 256, 0, stream>>>(inputs, ln1s, ln1b, bufA);

  // qk: fp32 (for buckets) + bf16 (for attention); v: bf16 only
  gemm_bt<3><<<64 * 8, 256, 0, stream>>>(bufA, wqk_bt, nullptr, nullptr, qkf,
                                         qb, 8192, 1024, 1024);
  gemm_bt<4><<<64 * 8, 256, 0, stream>>>(bufA, wv_bt, nullptr, nullptr, nullptr,
                                         vb, 8192, 1024, 1024);

  bucket_kernel<<<4096, 256, 0, stream>>>(qkf, rot, knb, buckets);
  sort_kernel<<<64, 256, 0, stream>>>(buckets, order);
  lsh_attn_mfma<<<2048, 256, 0, stream>>>(qb, knb, vb, order, obuf, slogb);
  combine_rounds<<<32768, 256, 0, stream>>>(obuf, slogb, bufA);

  gemm_bt<2><<<64 * 8, 256, 0, stream>>>(bufA, wout_bt, nullptr, inputs, x2,
                                         nullptr, 8192, 1024, 1024);
  ln_bf16<<<8192, 256, 0, stream>>>(x2, ln2s, ln2b, bufA);
  gemm_bt<1><<<64 * 32, 256, 0, stream>>>(bufA, wm1_bt, bm1, nullptr, nullptr,
                                          h1, 8192, 4096, 1024);
  gemm_bt<2><<<64 * 8, 256, 0, stream>>>(h1, wm2_bt, bm2, x2, (float*)d_out,
                                         nullptr, 8192, 1024, 4096);
}